// Round 11
// baseline (1999.000 us; speedup 1.0000x reference)
//
#include <hip/hip_runtime.h>
#include <cstdint>
#include <cstddef>

typedef unsigned long long u64;
typedef unsigned int u32;

constexpr int B_ = 2, C_ = 512, H_ = 50, W_ = 84, A_ = 15;
constexpr int HW_ = H_ * W_;        // 4200
constexpr int NS_ = HW_ * A_;       // 63000
constexpr int PRE_ = 6000, POST_ = 1000;
constexpr int WORDS_ = 94;          // ceil(6000/64)
constexpr int NPAD_ = 6016;
constexpr int SORTN_ = 8192;
constexpr double NMS_T = 0.7;
constexpr double CLIP_ = 4.1351665567423556;  // float(np.log(1000/16))
constexpr int OUT_ROIS_ = B_ * A_ * HW_ + B_ * 4 * A_ * HW_;  // 630000
constexpr int OUT_PROBS_ = OUT_ROIS_ + B_ * POST_ * 5;        // 640000

// ---------------- K0: weight cvt (co,ci,tap) -> f64 [(ci*9+tap)*512 + co] ----------------
__global__ void k_wt(const float* __restrict__ w, double* __restrict__ wt64) {
  int idx = blockIdx.x * 256 + threadIdx.x;
  if (idx >= C_ * C_ * 9) return;
  int co = idx & 511;
  int r = idx >> 9;
  int k = r % 9;
  int ci = r / 9;
  wt64[idx] = (double)w[(co * C_ + ci) * 9 + k];
}

// ---------------- K0b: zero h0,h1 for split-K atomic accumulation ----------------
__global__ void k_hzero(double* __restrict__ h0, double* __restrict__ h1) {
  size_t i = (size_t)blockIdx.x * 256 + threadIdx.x;
  if (i < (size_t)B_ * C_ * HW_) { h0[i] = 0.0; h1[i] = 0.0; }
}

// ---------------- K1: 3x3 conv 512->512, f64, SGPR weights, split-K=4 ----------------
// 128-thread blocks (2 waves x 8 co): finer residency granularity, wave-level code
// identical to proven R9 kernel. 32 ci-chunks per block.
// grid: (7 colb, 5 rowb, 256 = b*128 + cob*4 + q), cob in [0,32) covers 16 co.
// Quarters {0,1}->h0, {2,3}->h1: each buffer element gets exactly 2 atomicAdds
// onto 0.0 -> order-independent (IEEE).
__global__ __launch_bounds__(128) void k_conv3(const float* __restrict__ x,
                                               const double* __restrict__ wt64,
                                               double* __restrict__ h0,
                                               double* __restrict__ h1) {
  const int tid = threadIdx.x;
  const int lane = tid & 63;
  const int wid = __builtin_amdgcn_readfirstlane(tid >> 6);  // 0/1, wave-uniform
  const int cg = lane % 12;
  const int rowg = lane / 12;       // 0..4 valid, 5 = idle lane
  const bool act = (rowg < 5);
  const int colb = blockIdx.x;      // 0..6
  const int rowb = blockIdx.y;      // 0..4
  const int z = blockIdx.z;
  const int b = z >> 7;
  const int cob = (z >> 2) & 31;    // 16-co block
  const int q = z & 3;
  const int c0 = colb * 12;
  const int rblk = rowb * 10;
  const int col = c0 + cg;
  const int rg5 = act ? rowg : 4;   // clamp idle lanes to safe indices
  const int r0 = rblk + rg5 * 2;
  const int cstart = q * 32;        // cb4 chunk range [cstart, cstart+32)
  double* __restrict__ hp = (q < 2) ? h0 : h1;

  __shared__ double xs[4][14][14];  // [ci][col 12+2halo][row 12 used]

  double acc[2][8];
#pragma unroll
  for (int j = 0; j < 2; ++j)
#pragma unroll
    for (int c = 0; c < 8; ++c) acc[j][c] = 0.0;

  float xreg[6];
  auto loadX = [&](int cb4) {
#pragma unroll
    for (int k = 0; k < 6; ++k) {
      int s = tid + k * 128;
      float v = 0.f;
      if (s < 672) {
        int ci = s / 168;
        int r168 = s % 168;
        int rr = r168 / 14;
        int cc = r168 % 14;
        int gr = rblk - 1 + rr, gc = c0 - 1 + cc;
        if (gr >= 0 && gr < H_ && gc >= 0 && gc < W_)
          v = x[((b * C_ + cb4 * 4 + ci) * H_ + gr) * W_ + gc];
      }
      xreg[k] = v;
    }
  };
  auto storeX = [&]() {
#pragma unroll
    for (int k = 0; k < 6; ++k) {
      int s = tid + k * 128;
      if (s < 672) {
        int ci = s / 168;
        int r168 = s % 168;
        int rr = r168 / 14;
        int cc = r168 % 14;
        xs[ci][cc][rr] = (double)xreg[k];
      }
    }
  };

  // wave-uniform weight base: this wave's 8 output channels
  const double* __restrict__ wb = wt64 + (size_t)(cob * 16 + wid * 8);

  loadX(cstart);
  for (int it = 0; it < 32; ++it) {
    const int cb4 = cstart + it;
    __syncthreads();
    storeX();
    __syncthreads();
    if (it < 31) loadX(cb4 + 1);
#pragma unroll
    for (int ci = 0; ci < 4; ++ci) {
#pragma unroll
      for (int kx = 0; kx < 3; ++kx) {
        double xv[4];
        const double* xp = &xs[ci][cg + kx][rg5 * 2];
#pragma unroll
        for (int t = 0; t < 4; ++t) xv[t] = xp[t];
#pragma unroll
        for (int ky = 0; ky < 3; ++ky) {
          // wave-uniform address -> s_load, values live in SGPR pairs
          const double* __restrict__ wp =
              wb + ((size_t)(cb4 * 4 + ci) * 9 + (ky * 3 + kx)) * C_;
#pragma unroll
          for (int c = 0; c < 8; ++c) {
            double wv = wp[c];
            acc[0][c] = fma(xv[ky], wv, acc[0][c]);
            acc[1][c] = fma(xv[ky + 1], wv, acc[1][c]);
          }
        }
      }
    }
  }

  if (act) {
#pragma unroll
    for (int c = 0; c < 8; ++c) {
      int co = cob * 16 + wid * 8 + c;
#pragma unroll
      for (int j = 0; j < 2; ++j) {
        atomicAdd(&hp[((size_t)b * C_ + co) * HW_ + (r0 + j) * W_ + col], acc[j][c]);
      }
    }
  }
}

// ---------------- K2: 1x1 convs; folds h0+h1, conv bias+ReLU at load ----------------
__global__ __launch_bounds__(256) void k_conv1(const double* __restrict__ h0,
                                               const double* __restrict__ h1,
                                               const float* __restrict__ convb,
                                               const float* __restrict__ clsw,
                                               const float* __restrict__ clsb,
                                               const float* __restrict__ bbw,
                                               const float* __restrict__ bbb,
                                               float* __restrict__ out,
                                               double* __restrict__ scores,
                                               double* __restrict__ deltas) {
  const int b = blockIdx.y;
  const int p0 = blockIdx.x * 32;
  const int tid = threadIdx.x;
  const int px = tid & 31, cg = tid >> 5;  // 8 channel groups, 10 ch each
  __shared__ double hs[64][32];
  __shared__ double wl[64][80];
  double acc[10];
#pragma unroll
  for (int k = 0; k < 10; ++k) acc[k] = 0.0;
  for (int ci0 = 0; ci0 < C_; ci0 += 64) {
    for (int s = tid; s < 64 * 32; s += 256) {
      int ci = s >> 5, pp = s & 31;
      int p = p0 + pp;
      double v = 0.0;
      if (p < HW_) {
        size_t idx = ((size_t)b * C_ + ci0 + ci) * HW_ + p;
        v = (h0[idx] + h1[idx]) + (double)convb[ci0 + ci];
        v = v > 0.0 ? v : 0.0;   // ReLU(conv + bias)
      }
      hs[ci][pp] = v;
    }
    for (int s = tid; s < 64 * 80; s += 256) {
      int ci = s / 80, c = s % 80;
      double v = 0.0;
      if (c < 15) v = (double)clsw[c * C_ + ci0 + ci];
      else if (c < 75) v = (double)bbw[(c - 15) * C_ + ci0 + ci];
      wl[ci][c] = v;
    }
    __syncthreads();
    for (int ci = 0; ci < 64; ++ci) {
      double xv = hs[ci][px];
#pragma unroll
      for (int k = 0; k < 10; ++k)
        acc[k] = fma(wl[ci][cg * 10 + k], xv, acc[k]);
    }
    __syncthreads();
  }
  int p = p0 + px;
  if (p < HW_) {
#pragma unroll
    for (int k = 0; k < 10; ++k) {
      int c = cg * 10 + k;
      if (c < 15) {
        double z = acc[k] + (double)clsb[c];
        out[(size_t)b * NS_ + c * HW_ + p] = (float)z;
        double s = 1.0 / (1.0 + exp(-z));
        scores[(size_t)b * NS_ + (size_t)p * A_ + c] = s;
      } else if (c < 75) {
        int cbx = c - 15;
        double z = acc[k] + (double)bbb[cbx];
        out[(size_t)B_ * NS_ + (size_t)b * (4 * A_ * HW_) + cbx * HW_ + p] = (float)z;
        deltas[(size_t)b * (4 * NS_) + (size_t)p * (4 * A_) + cbx] = z;
      }
    }
  }
}

// ---------------- select: grid-parallel radix threshold (5 rounds) ----------------
__global__ void k_selzero(u64* __restrict__ selprefix, u32* __restrict__ selabove,
                          u32* __restrict__ selcnt, u32* __restrict__ selhist) {
  int t = blockIdx.x * 256 + threadIdx.x;
  if (t < 2) { selprefix[t] = 0ull; selabove[t] = 0u; selcnt[t] = 0u; }
  if (t < 512) selhist[t] = 0u;
}

__global__ __launch_bounds__(256) void k_hist(const double* __restrict__ scores,
                                              const u64* __restrict__ selprefix,
                                              u32* __restrict__ selhist, int r) {
  const int b = blockIdx.y;
  const double* sc = scores + (size_t)b * NS_;
  const int lane = (int)(threadIdx.x & 63);
  const int shift = 56 - 8 * r;
  const u64 prefix = selprefix[b];
  const u64 himask = (r == 0) ? 0ull : (~0ull << (shift + 8));
  for (int i = blockIdx.x * 256 + (int)threadIdx.x; i < NS_; i += 64 * 256) {
    u64 k = (u64)__double_as_longlong(sc[i]);
    bool valid = ((k & himask) == (prefix & himask));
    u32 d = (u32)((k >> shift) & 255);
    u64 m = __ballot(valid);
#pragma unroll
    for (int bit = 0; bit < 8; ++bit) {
      u64 bb = __ballot((d >> bit) & 1);
      m &= ((d >> bit) & 1) ? bb : ~bb;
    }
    if (valid && lane == (__ffsll((unsigned long long)m) - 1))
      atomicAdd(&selhist[b * 256 + (int)d], (u32)__popcll(m));
  }
}

__global__ void k_pick(u64* __restrict__ selprefix, u32* __restrict__ selabove,
                       u32* __restrict__ selhist, int r) {
  const int b = blockIdx.x;
  __shared__ u32 hsm[256];
  hsm[threadIdx.x] = selhist[b * 256 + threadIdx.x];
  __syncthreads();
  if (threadIdx.x == 0) {
    const int shift = 56 - 8 * r;
    u32 c = selabove[b];
    int dsel = 0;
    for (int dd = 255; dd >= 0; --dd) {
      u32 nc = c + hsm[dd];
      if (nc >= (u32)PRE_) { dsel = dd; break; }
      c = nc;
    }
    selprefix[b] |= ((u64)dsel << shift);
    selabove[b] = c;
  }
  __syncthreads();
  selhist[b * 256 + threadIdx.x] = 0u;  // ready for next round
}

__global__ __launch_bounds__(256) void k_compact(const double* __restrict__ scores,
                                                 const u64* __restrict__ selprefix,
                                                 u32* __restrict__ selcnt,
                                                 u64* __restrict__ selk,
                                                 u32* __restrict__ seli) {
  const int b = blockIdx.y;
  const double* sc = scores + (size_t)b * NS_;
  const int lane = (int)(threadIdx.x & 63);
  const u64 T = selprefix[b];
  for (int i = blockIdx.x * 256 + (int)threadIdx.x; i < NS_; i += 64 * 256) {
    u64 k = (u64)__double_as_longlong(sc[i]);
    bool q = (k >= T);
    u64 bal = __ballot(q);
    if (bal) {
      int leader = __ffsll((unsigned long long)bal) - 1;
      u32 wbase = 0;
      if (lane == leader) wbase = atomicAdd(&selcnt[b], (u32)__popcll(bal));
      wbase = (u32)__shfl((int)wbase, leader);
      if (q) {
        u64 below = (lane == 0) ? 0ull : (~0ull >> (64 - lane));
        u32 pos = wbase + (u32)__popcll(bal & below);
        if (pos < (u32)SORTN_) {
          selk[(size_t)b * SORTN_ + pos] = k;
          seli[(size_t)b * SORTN_ + pos] = (u32)i;
        }
      }
    }
  }
}

// ---------------- K4: parallel rank sort (desc by score bits, asc idx) ----------------
// Each thread owns one candidate e < cnt and counts how many candidates outrank it
// under the total order (key desc, idx asc). Deterministic regardless of the
// nondeterministic storage order from k_compact. Stale slots j >= cnt never read.
__global__ __launch_bounds__(1024) void k_rank(const u64* __restrict__ selk,
                                               const u32* __restrict__ seli,
                                               const u32* __restrict__ selcnt,
                                               double* __restrict__ ssc,
                                               u32* __restrict__ sidx) {
  const int b = blockIdx.y;
  const int e = blockIdx.x * 1024 + (int)threadIdx.x;
  int mn = (int)selcnt[b];
  if (mn > SORTN_) mn = SORTN_;
  const bool active = (e < mn);
  u64 ke = 0; u32 ie = 0;
  if (active) {
    ke = selk[(size_t)b * SORTN_ + e];
    ie = seli[(size_t)b * SORTN_ + e];
  }
  __shared__ u64 ks[1024];
  __shared__ u32 isx[1024];
  int rank = 0;
  for (int t0 = 0; t0 < mn; t0 += 1024) {
    int j = t0 + (int)threadIdx.x;
    if (j < mn) {
      ks[threadIdx.x] = selk[(size_t)b * SORTN_ + j];
      isx[threadIdx.x] = seli[(size_t)b * SORTN_ + j];
    }
    __syncthreads();
    int lim = mn - t0;
    if (lim > 1024) lim = 1024;
    if (active) {
      for (int j2 = 0; j2 < lim; ++j2) {
        u64 kj = ks[j2];
        bool better = (kj > ke) || (kj == ke && isx[j2] < ie);
        rank += better ? 1 : 0;
      }
    }
    __syncthreads();
  }
  if (active && rank < PRE_) {
    ssc[(size_t)b * PRE_ + rank] = __longlong_as_double((long long)ke);
    sidx[(size_t)b * PRE_ + rank] = ie;
  }
}

// ---------------- K5: box decode + clip + valid (f64, contract off) ----------------
__global__ __launch_bounds__(256) void k_decode(const u32* __restrict__ sidx,
                                                const double* __restrict__ deltas,
                                                const float* __restrict__ anchors,
                                                const float* __restrict__ iminfo,
                                                double* __restrict__ boxes,
                                                double* __restrict__ areas,
                                                u64* __restrict__ vmask) {
#pragma clang fp contract(off)
  const int b = blockIdx.y;
  const int i = blockIdx.x * 256 + (int)threadIdx.x;
  bool valid = false;
  if (i < NPAD_) {
    double x1 = 0, y1 = 0, x2 = 0, y2 = 0, ar = 0;
    if (i < PRE_) {
      u32 idx = sidx[(size_t)b * PRE_ + i];
      int p = (int)idx / A_, a = (int)idx % A_;
      int yy = p / W_, xx = p % W_;
      double sx = xx * 16.0, sy = yy * 16.0;
      double b0 = sx + (double)anchors[a * 4 + 0];
      double b1 = sy + (double)anchors[a * 4 + 1];
      double b2 = sx + (double)anchors[a * 4 + 2];
      double b3 = sy + (double)anchors[a * 4 + 3];
      double wdt = b2 - b0 + 1.0, hgt = b3 - b1 + 1.0;
      double cx = b0 + 0.5 * wdt, cy = b1 + 0.5 * hgt;
      const double* d = deltas + (size_t)b * (4 * NS_) + (size_t)idx * 4;
      double dx = d[0], dy = d[1];
      double dw = d[2] < CLIP_ ? d[2] : CLIP_;
      double dh = d[3] < CLIP_ ? d[3] : CLIP_;
      double pcx = dx * wdt + cx, pcy = dy * hgt + cy;
      double pw = exp(dw) * wdt, ph = exp(dh) * hgt;
      x1 = pcx - 0.5 * pw;
      y1 = pcy - 0.5 * ph;
      x2 = pcx + 0.5 * pw - 1.0;
      y2 = pcy + 0.5 * ph - 1.0;
      double imh = (double)iminfo[b * 3 + 0];
      double imw = (double)iminfo[b * 3 + 1];
      x1 = x1 < 0.0 ? 0.0 : (x1 > imw - 1.0 ? imw - 1.0 : x1);
      y1 = y1 < 0.0 ? 0.0 : (y1 > imh - 1.0 ? imh - 1.0 : y1);
      x2 = x2 < 0.0 ? 0.0 : (x2 > imw - 1.0 ? imw - 1.0 : x2);
      y2 = y2 < 0.0 ? 0.0 : (y2 > imh - 1.0 ? imh - 1.0 : y2);
      double wss = x2 - x1 + 1.0, hss = y2 - y1 + 1.0;
      double xc = x1 + wss / 2.0, yc = y1 + hss / 2.0;
      valid = (wss >= 0.0) && (hss >= 0.0) && (xc < imw) && (yc < imh);
      ar = wss * hss;
    }
    double* bx = boxes + ((size_t)b * NPAD_ + i) * 4;
    bx[0] = x1; bx[1] = y1; bx[2] = x2; bx[3] = y2;
    areas[(size_t)b * NPAD_ + i] = ar;
  }
  u64 bal = __ballot(valid);
  if ((threadIdx.x & 63) == 0) {
    int w = i >> 6;
    if (w < WORDS_) vmask[b * WORDS_ + w] = bal;
  }
}

// ---------------- K6: suppression bitmask (iou > 0.7 & j > i) ----------------
__global__ __launch_bounds__(64) void k_mask(const double* __restrict__ boxes,
                                             const double* __restrict__ areas,
                                             u64* __restrict__ mask) {
#pragma clang fp contract(off)
  const int b = blockIdx.z;
  const int wc = blockIdx.x, rb = blockIdx.y;
  const int i = rb * 64 + (int)threadIdx.x;
  if (wc < rb) {
    if (i < PRE_) mask[((size_t)b * NPAD_ + i) * WORDS_ + wc] = 0ull;
    return;
  }
  __shared__ double cbx[64][4];
  __shared__ double car[64];
  {
    int sj = wc * 64 + (int)threadIdx.x;  // <= 6015 < NPAD_
    const double* pj = boxes + ((size_t)b * NPAD_ + sj) * 4;
    cbx[threadIdx.x][0] = pj[0];
    cbx[threadIdx.x][1] = pj[1];
    cbx[threadIdx.x][2] = pj[2];
    cbx[threadIdx.x][3] = pj[3];
    car[threadIdx.x] = areas[(size_t)b * NPAD_ + sj];
  }
  __syncthreads();
  if (i >= PRE_) return;
  const double* bi = boxes + ((size_t)b * NPAD_ + i) * 4;
  double x1 = bi[0], y1 = bi[1], x2 = bi[2], y2 = bi[3];
  double ai = areas[(size_t)b * NPAD_ + i];
  u64 m = 0;
  int jmax = PRE_ - wc * 64;
  if (jmax > 64) jmax = 64;
  for (int j2 = 0; j2 < jmax; ++j2) {
    int j = wc * 64 + j2;
    if (j > i) {
      double ix1 = x1 > cbx[j2][0] ? x1 : cbx[j2][0];
      double iy1 = y1 > cbx[j2][1] ? y1 : cbx[j2][1];
      double ix2 = x2 < cbx[j2][2] ? x2 : cbx[j2][2];
      double iy2 = y2 < cbx[j2][3] ? y2 : cbx[j2][3];
      double iw = ix2 - ix1 + 1.0;
      if (iw < 0.0) iw = 0.0;
      double ih = iy2 - iy1 + 1.0;
      if (ih < 0.0) ih = 0.0;
      double inter = iw * ih;
      double iou = inter / (ai + car[j2] - inter);
      if (iou > NMS_T) m |= (1ull << j2);
    }
  }
  mask[((size_t)b * NPAD_ + i) * WORDS_ + wc] = m;
}

// ---------------- K7: greedy NMS closure scan (survivor chain, 4-wide batched ORs) ----------------
__global__ __launch_bounds__(64) void k_scan(const u64* __restrict__ mask,
                                             const u64* __restrict__ vmask,
                                             u64* __restrict__ keepm) {
  const int b = blockIdx.x;
  const int lane = (int)threadIdx.x;
  u64 rem0 = ~vmask[b * WORDS_ + lane];  // lane holds word `lane` (dead-bits)
  u64 rem1 = (lane < WORDS_ - 64) ? ~vmask[b * WORDS_ + 64 + lane] : ~0ull;
  int kept = 0;
  int Bb = 0;
  for (; Bb < WORDS_ && kept < POST_; ++Bb) {
    const int base = Bb * 64;
    int lim = PRE_ - base;
    if (lim > 64) lim = 64;
    u64 cur = (Bb < 64) ? __shfl(rem0, Bb) : __shfl(rem1, Bb - 64);
    if (lim < 64) cur |= (~0ull) << lim;
    u64 dg = (lane < lim) ? mask[((size_t)b * NPAD_ + base + lane) * WORDS_ + Bb] : 0ull;
    u64 kb = 0;
    while (cur != ~0ull) {
      int t = __ffsll((unsigned long long)~cur) - 1;
      kb |= 1ull << t;
      cur |= __shfl(dg, t);
      cur |= 1ull << t;
      if (++kept >= POST_) break;
    }
    // deferred row-ORs, 4 rows' loads in flight per step (kb is wave-uniform)
    u64 or0 = 0, or1 = 0;
    u64 k2 = kb;
    const u64* mb = mask + (size_t)b * NPAD_ * WORDS_;
    while (k2) {
      int t0 = __ffsll((unsigned long long)k2) - 1; k2 &= k2 - 1;
      int t1 = -1, t2 = -1, t3 = -1;
      if (k2) { t1 = __ffsll((unsigned long long)k2) - 1; k2 &= k2 - 1; }
      if (k2) { t2 = __ffsll((unsigned long long)k2) - 1; k2 &= k2 - 1; }
      if (k2) { t3 = __ffsll((unsigned long long)k2) - 1; k2 &= k2 - 1; }
      const u64* m0 = mb + (size_t)(base + t0) * WORDS_;
      u64 a0 = m0[lane];
      u64 a1 = (lane < WORDS_ - 64) ? m0[64 + lane] : 0ull;
      u64 b0 = 0, b1 = 0, c0 = 0, c1 = 0, d0 = 0, d1 = 0;
      if (t1 >= 0) {
        const u64* m1 = mb + (size_t)(base + t1) * WORDS_;
        b0 = m1[lane]; b1 = (lane < WORDS_ - 64) ? m1[64 + lane] : 0ull;
      }
      if (t2 >= 0) {
        const u64* m2 = mb + (size_t)(base + t2) * WORDS_;
        c0 = m2[lane]; c1 = (lane < WORDS_ - 64) ? m2[64 + lane] : 0ull;
      }
      if (t3 >= 0) {
        const u64* m3 = mb + (size_t)(base + t3) * WORDS_;
        d0 = m3[lane]; d1 = (lane < WORDS_ - 64) ? m3[64 + lane] : 0ull;
      }
      or0 |= (a0 | b0) | (c0 | d0);
      or1 |= (a1 | b1) | (c1 | d1);
    }
    rem0 |= or0;
    rem1 |= or1;
    if (lane == 0) keepm[b * WORDS_ + Bb] = kb;
  }
  for (int w = Bb + lane; w < WORDS_; w += 64)
    keepm[b * WORDS_ + w] = 0ull;
}

// ---------------- K8: finalize rois + probs (kept in order, then not-kept with -1) ----------------
__global__ __launch_bounds__(256) void k_final(const u64* __restrict__ keepm,
                                               const double* __restrict__ boxes,
                                               const double* __restrict__ ssc,
                                               float* __restrict__ out) {
  const int b = blockIdx.x;
  __shared__ u32 pk[WORDS_ + 1];
  __shared__ u64 km_s[WORDS_];
  for (int w = threadIdx.x; w < WORDS_; w += 256) km_s[w] = keepm[b * WORDS_ + w];
  __syncthreads();
  if (threadIdx.x == 0) {
    u32 a = 0;
    for (int w = 0; w < WORDS_; ++w) {
      pk[w] = a;
      a += (u32)__popcll(km_s[w]);
    }
    pk[WORDS_] = a;
  }
  __syncthreads();
  const u32 K = pk[WORDS_];
  for (int i = threadIdx.x; i < PRE_; i += 256) {
    int w = i >> 6, t = i & 63;
    u64 km = km_s[w];
    u32 before = pk[w] + (u32)__popcll(km & ((1ull << t) - 1ull));
    bool kp = (km >> t) & 1ull;
    int slot = kp ? (int)before : (int)K + (i - (int)before);
    if (slot < POST_) {
      const double* bx = boxes + ((size_t)b * NPAD_ + i) * 4;
      float* ro = out + OUT_ROIS_ + ((size_t)b * POST_ + slot) * 5;
      ro[0] = (float)b;
      ro[1] = (float)bx[0];
      ro[2] = (float)bx[1];
      ro[3] = (float)bx[2];
      ro[4] = (float)bx[3];
      out[OUT_PROBS_ + b * POST_ + slot] = kp ? (float)ssc[(size_t)b * PRE_ + i] : -1.0f;
    }
  }
}

extern "C" void kernel_launch(void* const* d_in, const int* in_sizes, int n_in,
                              void* d_out, int out_size, void* d_ws, size_t ws_size,
                              hipStream_t stream) {
  (void)in_sizes; (void)n_in; (void)out_size; (void)ws_size;
  const float* x = (const float*)d_in[0];
  const float* iminfo = (const float*)d_in[1];
  const float* convw = (const float*)d_in[2];
  const float* convb = (const float*)d_in[3];
  const float* clsw = (const float*)d_in[4];
  const float* clsb = (const float*)d_in[5];
  const float* bbw = (const float*)d_in[6];
  const float* bbb = (const float*)d_in[7];
  const float* anchors = (const float*)d_in[8];
  float* out = (float*)d_out;

  char* ws = (char*)d_ws;
  size_t off = 0;
  auto alloc = [&](size_t bytes) -> void* {
    void* p = ws + off;
    off += (bytes + 255) & ~(size_t)255;
    return p;
  };
  double* wt64 = (double*)alloc((size_t)C_ * 9 * C_ * 8);       // 18.9 MB
  double* h0 = (double*)alloc((size_t)B_ * C_ * HW_ * 8);       // 34.4 MB
  double* h1 = (double*)alloc((size_t)B_ * C_ * HW_ * 8);       // 34.4 MB
  double* scores = (double*)alloc((size_t)B_ * NS_ * 8);        // 1 MB
  double* deltas = (double*)alloc((size_t)B_ * NS_ * 4 * 8);    // 4 MB
  u64* selk = (u64*)alloc((size_t)B_ * SORTN_ * 8);
  u32* seli = (u32*)alloc((size_t)B_ * SORTN_ * 4);
  double* ssc = (double*)alloc((size_t)B_ * PRE_ * 8);
  u32* sidx = (u32*)alloc((size_t)B_ * PRE_ * 4);
  double* boxes = (double*)alloc((size_t)B_ * NPAD_ * 4 * 8);
  double* areas = (double*)alloc((size_t)B_ * NPAD_ * 8);
  u64* vmask = (u64*)alloc((size_t)B_ * WORDS_ * 8);
  u64* mask = (u64*)alloc((size_t)B_ * NPAD_ * WORDS_ * 8);     // 9 MB
  u64* keepm = (u64*)alloc((size_t)B_ * WORDS_ * 8);
  u64* selprefix = (u64*)alloc(2 * 8);
  u32* selabove = (u32*)alloc(2 * 4);
  u32* selcnt = (u32*)alloc(2 * 4);
  u32* selhist = (u32*)alloc(512 * 4);

  k_wt<<<(C_ * C_ * 9 + 255) / 256, 256, 0, stream>>>(convw, wt64);
  k_hzero<<<(B_ * C_ * HW_ + 255) / 256, 256, 0, stream>>>(h0, h1);
  k_conv3<<<dim3(7, 5, 256), 128, 0, stream>>>(x, wt64, h0, h1);
  k_conv1<<<dim3(132, 2), 256, 0, stream>>>(h0, h1, convb, clsw, clsb, bbw, bbb, out, scores, deltas);
  k_selzero<<<2, 256, 0, stream>>>(selprefix, selabove, selcnt, selhist);
  for (int r = 0; r < 5; ++r) {
    k_hist<<<dim3(64, 2), 256, 0, stream>>>(scores, selprefix, selhist, r);
    k_pick<<<2, 256, 0, stream>>>(selprefix, selabove, selhist, r);
  }
  k_compact<<<dim3(64, 2), 256, 0, stream>>>(scores, selprefix, selcnt, selk, seli);
  k_rank<<<dim3(8, 2), 1024, 0, stream>>>(selk, seli, selcnt, ssc, sidx);
  k_decode<<<dim3(24, 2), 256, 0, stream>>>(sidx, deltas, anchors, iminfo, boxes, areas, vmask);
  k_mask<<<dim3(94, 94, 2), 64, 0, stream>>>(boxes, areas, mask);
  k_scan<<<2, 64, 0, stream>>>(mask, vmask, keepm);
  k_final<<<2, 256, 0, stream>>>(keepm, boxes, ssc, out);
}

// Round 13
// 1859.439 us; speedup vs baseline: 1.0751x; 1.0751x over previous
//
#include <hip/hip_runtime.h>
#include <cstdint>
#include <cstddef>

typedef unsigned long long u64;
typedef unsigned int u32;

constexpr int B_ = 2, C_ = 512, H_ = 50, W_ = 84, A_ = 15;
constexpr int HW_ = H_ * W_;        // 4200
constexpr int NS_ = HW_ * A_;       // 63000
constexpr int PRE_ = 6000, POST_ = 1000;
constexpr int WORDS_ = 94;          // ceil(6000/64)
constexpr int NPAD_ = 6016;
constexpr int SORTN_ = 8192;
constexpr double NMS_T = 0.7;
constexpr double CLIP_ = 4.1351665567423556;  // float(np.log(1000/16))
constexpr int OUT_ROIS_ = B_ * A_ * HW_ + B_ * 4 * A_ * HW_;  // 630000
constexpr int OUT_PROBS_ = OUT_ROIS_ + B_ * POST_ * 5;        // 640000
constexpr int NROUNDS_ = 5;

// ---------------- K_init: weight cvt + zero h0/h1, mask, select state ----------------
__global__ void k_init(const float* __restrict__ w, double* __restrict__ wt64,
                       double* __restrict__ h0, double* __restrict__ h1,
                       u64* __restrict__ mask, u32* __restrict__ selcnt,
                       u32* __restrict__ selhist) {
  int idx = blockIdx.x * 256 + threadIdx.x;
  if (idx < C_ * C_ * 9) {
    int co = idx & 511;
    int r = idx >> 9;
    int k = r % 9;
    int ci = r / 9;
    wt64[idx] = (double)w[(co * C_ + ci) * 9 + k];
  }
  if (idx < B_ * C_ * HW_) { h0[idx] = 0.0; h1[idx] = 0.0; }
  if (idx < B_ * NPAD_ * WORDS_) mask[idx] = 0ull;
  if (idx < 2) selcnt[idx] = 0u;
  if (idx < NROUNDS_ * 2 * 256) selhist[idx] = 0u;
}

// ---------------- K1: 3x3 conv 512->512, f64, SGPR weights, split-K=4 (R9 proven) ----------------
// block: 256 thr = 4 waves. wave -> 8 co. lane = 12 cols x 5 rowg (60 used).
// grid: (7 colb, 5 rowb, 128 = b*64 + cob*4 + q). Quarters {0,1}->h0, {2,3}->h1:
// each buffer element gets exactly 2 atomicAdds onto 0.0 -> order-independent (IEEE).
__global__ __launch_bounds__(256) void k_conv3(const float* __restrict__ x,
                                               const double* __restrict__ wt64,
                                               double* __restrict__ h0,
                                               double* __restrict__ h1) {
  const int tid = threadIdx.x;
  const int lane = tid & 63;
  const int wid = __builtin_amdgcn_readfirstlane(tid >> 6);  // wave-uniform co group
  const int cg = lane % 12;
  const int rowg = lane / 12;       // 0..4 valid, 5 = idle lane
  const bool act = (rowg < 5);
  const int colb = blockIdx.x;      // 0..6
  const int rowb = blockIdx.y;      // 0..4
  const int z = blockIdx.z;
  const int b = z >> 6;
  const int cob = (z >> 2) & 15;
  const int q = z & 3;
  const int c0 = colb * 12;
  const int rblk = rowb * 10;
  const int col = c0 + cg;
  const int rg5 = act ? rowg : 4;   // clamp idle lanes to safe indices
  const int r0 = rblk + rg5 * 2;
  const int cstart = q * 32;        // cb4 chunk range [cstart, cstart+32)
  double* __restrict__ hp = (q < 2) ? h0 : h1;

  __shared__ double xs[4][14][14];  // [ci][col 12+2halo][row 12 used]

  double acc[2][8];
#pragma unroll
  for (int j = 0; j < 2; ++j)
#pragma unroll
    for (int c = 0; c < 8; ++c) acc[j][c] = 0.0;

  float xreg[3];
  auto loadX = [&](int cb4) {
#pragma unroll
    for (int k = 0; k < 3; ++k) {
      int s = tid + k * 256;
      float v = 0.f;
      if (s < 672) {
        int ci = s / 168;
        int r168 = s % 168;
        int rr = r168 / 14;
        int cc = r168 % 14;
        int gr = rblk - 1 + rr, gc = c0 - 1 + cc;
        if (gr >= 0 && gr < H_ && gc >= 0 && gc < W_)
          v = x[((b * C_ + cb4 * 4 + ci) * H_ + gr) * W_ + gc];
      }
      xreg[k] = v;
    }
  };
  auto storeX = [&]() {
#pragma unroll
    for (int k = 0; k < 3; ++k) {
      int s = tid + k * 256;
      if (s < 672) {
        int ci = s / 168;
        int r168 = s % 168;
        int rr = r168 / 14;
        int cc = r168 % 14;
        xs[ci][cc][rr] = (double)xreg[k];
      }
    }
  };

  // wave-uniform weight base: this wave's 8 output channels
  const double* __restrict__ wb = wt64 + (size_t)(cob * 32 + wid * 8);

  loadX(cstart);
  for (int it = 0; it < 32; ++it) {
    const int cb4 = cstart + it;
    __syncthreads();
    storeX();
    __syncthreads();
    if (it < 31) loadX(cb4 + 1);
#pragma unroll
    for (int ci = 0; ci < 4; ++ci) {
#pragma unroll
      for (int kx = 0; kx < 3; ++kx) {
        double xv[4];
        const double* xp = &xs[ci][cg + kx][rg5 * 2];
#pragma unroll
        for (int t = 0; t < 4; ++t) xv[t] = xp[t];
#pragma unroll
        for (int ky = 0; ky < 3; ++ky) {
          // wave-uniform address -> s_load, values live in SGPR pairs
          const double* __restrict__ wp =
              wb + ((size_t)(cb4 * 4 + ci) * 9 + (ky * 3 + kx)) * C_;
#pragma unroll
          for (int c = 0; c < 8; ++c) {
            double wv = wp[c];
            acc[0][c] = fma(xv[ky], wv, acc[0][c]);
            acc[1][c] = fma(xv[ky + 1], wv, acc[1][c]);
          }
        }
      }
    }
  }

  if (act) {
#pragma unroll
    for (int c = 0; c < 8; ++c) {
      int co = cob * 32 + wid * 8 + c;
#pragma unroll
      for (int j = 0; j < 2; ++j) {
        atomicAdd(&hp[((size_t)b * C_ + co) * HW_ + (r0 + j) * W_ + col], acc[j][c]);
      }
    }
  }
}

// ---------------- K2: 1x1 convs; folds h0+h1, conv bias+ReLU at load ----------------
__global__ __launch_bounds__(256) void k_conv1(const double* __restrict__ h0,
                                               const double* __restrict__ h1,
                                               const float* __restrict__ convb,
                                               const float* __restrict__ clsw,
                                               const float* __restrict__ clsb,
                                               const float* __restrict__ bbw,
                                               const float* __restrict__ bbb,
                                               float* __restrict__ out,
                                               double* __restrict__ scores,
                                               double* __restrict__ deltas) {
  const int b = blockIdx.y;
  const int p0 = blockIdx.x * 32;
  const int tid = threadIdx.x;
  const int px = tid & 31, cg = tid >> 5;  // 8 channel groups, 10 ch each
  __shared__ double hs[64][32];
  __shared__ double wl[64][80];
  double acc[10];
#pragma unroll
  for (int k = 0; k < 10; ++k) acc[k] = 0.0;
  for (int ci0 = 0; ci0 < C_; ci0 += 64) {
    for (int s = tid; s < 64 * 32; s += 256) {
      int ci = s >> 5, pp = s & 31;
      int p = p0 + pp;
      double v = 0.0;
      if (p < HW_) {
        size_t idx = ((size_t)b * C_ + ci0 + ci) * HW_ + p;
        v = (h0[idx] + h1[idx]) + (double)convb[ci0 + ci];
        v = v > 0.0 ? v : 0.0;   // ReLU(conv + bias)
      }
      hs[ci][pp] = v;
    }
    for (int s = tid; s < 64 * 80; s += 256) {
      int ci = s / 80, c = s % 80;
      double v = 0.0;
      if (c < 15) v = (double)clsw[c * C_ + ci0 + ci];
      else if (c < 75) v = (double)bbw[(c - 15) * C_ + ci0 + ci];
      wl[ci][c] = v;
    }
    __syncthreads();
    for (int ci = 0; ci < 64; ++ci) {
      double xv = hs[ci][px];
#pragma unroll
      for (int k = 0; k < 10; ++k)
        acc[k] = fma(wl[ci][cg * 10 + k], xv, acc[k]);
    }
    __syncthreads();
  }
  int p = p0 + px;
  if (p < HW_) {
#pragma unroll
    for (int k = 0; k < 10; ++k) {
      int c = cg * 10 + k;
      if (c < 15) {
        double z = acc[k] + (double)clsb[c];
        out[(size_t)b * NS_ + c * HW_ + p] = (float)z;
        double s = 1.0 / (1.0 + exp(-z));
        scores[(size_t)b * NS_ + (size_t)p * A_ + c] = s;
      } else if (c < 75) {
        int cbx = c - 15;
        double z = acc[k] + (double)bbb[cbx];
        out[(size_t)B_ * NS_ + (size_t)b * (4 * A_ * HW_) + cbx * HW_ + p] = (float)z;
        deltas[(size_t)b * (4 * NS_) + (size_t)p * (4 * A_) + cbx] = z;
      }
    }
  }
}

// ---------------- select: prefix recomputation (deterministic integer scan) ----------------
__device__ inline u64 compute_prefix(const u32* __restrict__ selhist, int b, int rounds) {
  u64 prefix = 0;
  u32 above = 0;
  for (int rr = 0; rr < rounds; ++rr) {
    const u32* h = selhist + (rr * 2 + b) * 256;
    int shift = 56 - 8 * rr;
    u32 c = above;
    int dsel = 0;
    for (int dd = 255; dd >= 0; --dd) {
      u32 nc = c + h[dd];
      if (nc >= (u32)PRE_) { dsel = dd; break; }
      c = nc;
    }
    prefix |= ((u64)dsel << shift);
    above = c;
  }
  return prefix;
}

__global__ __launch_bounds__(256) void k_hist(const double* __restrict__ scores,
                                              u32* __restrict__ selhist, int r) {
  const int b = blockIdx.y;
  const double* sc = scores + (size_t)b * NS_;
  const int lane = (int)(threadIdx.x & 63);
  const int shift = 56 - 8 * r;
  __shared__ u64 sh_prefix;
  if (threadIdx.x == 0) sh_prefix = (r == 0) ? 0ull : compute_prefix(selhist, b, r);
  __syncthreads();
  const u64 prefix = sh_prefix;
  const u64 himask = (r == 0) ? 0ull : (~0ull << (shift + 8));
  u32* hist = selhist + (r * 2 + b) * 256;
  for (int i = blockIdx.x * 256 + (int)threadIdx.x; i < NS_; i += 64 * 256) {
    u64 k = (u64)__double_as_longlong(sc[i]);
    bool valid = ((k & himask) == (prefix & himask));
    u32 d = (u32)((k >> shift) & 255);
    u64 m = __ballot(valid);
#pragma unroll
    for (int bit = 0; bit < 8; ++bit) {
      u64 bb = __ballot((d >> bit) & 1);
      m &= ((d >> bit) & 1) ? bb : ~bb;
    }
    if (valid && lane == (__ffsll((unsigned long long)m) - 1))
      atomicAdd(&hist[d], (u32)__popcll(m));
  }
}

__global__ __launch_bounds__(256) void k_compact(const double* __restrict__ scores,
                                                 const u32* __restrict__ selhist,
                                                 u32* __restrict__ selcnt,
                                                 u64* __restrict__ selk,
                                                 u32* __restrict__ seli) {
  const int b = blockIdx.y;
  const double* sc = scores + (size_t)b * NS_;
  const int lane = (int)(threadIdx.x & 63);
  __shared__ u64 sh_T;
  if (threadIdx.x == 0) sh_T = compute_prefix(selhist, b, NROUNDS_);
  __syncthreads();
  const u64 T = sh_T;
  for (int i = blockIdx.x * 256 + (int)threadIdx.x; i < NS_; i += 64 * 256) {
    u64 k = (u64)__double_as_longlong(sc[i]);
    bool q = (k >= T);
    u64 bal = __ballot(q);
    if (bal) {
      int leader = __ffsll((unsigned long long)bal) - 1;
      u32 wbase = 0;
      if (lane == leader) wbase = atomicAdd(&selcnt[b], (u32)__popcll(bal));
      wbase = (u32)__shfl((int)wbase, leader);
      if (q) {
        u64 below = (lane == 0) ? 0ull : (~0ull >> (64 - lane));
        u32 pos = wbase + (u32)__popcll(bal & below);
        if (pos < (u32)SORTN_) {
          selk[(size_t)b * SORTN_ + pos] = k;
          seli[(size_t)b * SORTN_ + pos] = (u32)i;
        }
      }
    }
  }
}

// ---------------- K4: parallel rank sort (desc by score bits, asc idx) ----------------
__global__ __launch_bounds__(1024) void k_rank(const u64* __restrict__ selk,
                                               const u32* __restrict__ seli,
                                               const u32* __restrict__ selcnt,
                                               double* __restrict__ ssc,
                                               u32* __restrict__ sidx) {
  const int b = blockIdx.y;
  const int e = blockIdx.x * 1024 + (int)threadIdx.x;
  int mn = (int)selcnt[b];
  if (mn > SORTN_) mn = SORTN_;
  const bool active = (e < mn);
  u64 ke = 0; u32 ie = 0;
  if (active) {
    ke = selk[(size_t)b * SORTN_ + e];
    ie = seli[(size_t)b * SORTN_ + e];
  }
  __shared__ u64 ks[1024];
  __shared__ u32 isx[1024];
  int rank = 0;
  for (int t0 = 0; t0 < mn; t0 += 1024) {
    int j = t0 + (int)threadIdx.x;
    if (j < mn) {
      ks[threadIdx.x] = selk[(size_t)b * SORTN_ + j];
      isx[threadIdx.x] = seli[(size_t)b * SORTN_ + j];
    }
    __syncthreads();
    int lim = mn - t0;
    if (lim > 1024) lim = 1024;
    if (active) {
      for (int j2 = 0; j2 < lim; ++j2) {
        u64 kj = ks[j2];
        bool better = (kj > ke) || (kj == ke && isx[j2] < ie);
        rank += better ? 1 : 0;
      }
    }
    __syncthreads();
  }
  if (active && rank < PRE_) {
    ssc[(size_t)b * PRE_ + rank] = __longlong_as_double((long long)ke);
    sidx[(size_t)b * PRE_ + rank] = ie;
  }
}

// ---------------- K5: box decode + clip + valid (f64, contract off) ----------------
__global__ __launch_bounds__(256) void k_decode(const u32* __restrict__ sidx,
                                                const double* __restrict__ deltas,
                                                const float* __restrict__ anchors,
                                                const float* __restrict__ iminfo,
                                                double* __restrict__ boxes,
                                                double* __restrict__ areas,
                                                u64* __restrict__ vmask) {
#pragma clang fp contract(off)
  const int b = blockIdx.y;
  const int i = blockIdx.x * 256 + (int)threadIdx.x;
  bool valid = false;
  if (i < NPAD_) {
    double x1 = 0, y1 = 0, x2 = 0, y2 = 0, ar = 0;
    if (i < PRE_) {
      u32 idx = sidx[(size_t)b * PRE_ + i];
      int p = (int)idx / A_, a = (int)idx % A_;
      int yy = p / W_, xx = p % W_;
      double sx = xx * 16.0, sy = yy * 16.0;
      double b0 = sx + (double)anchors[a * 4 + 0];
      double b1 = sy + (double)anchors[a * 4 + 1];
      double b2 = sx + (double)anchors[a * 4 + 2];
      double b3 = sy + (double)anchors[a * 4 + 3];
      double wdt = b2 - b0 + 1.0, hgt = b3 - b1 + 1.0;
      double cx = b0 + 0.5 * wdt, cy = b1 + 0.5 * hgt;
      const double* d = deltas + (size_t)b * (4 * NS_) + (size_t)idx * 4;
      double dx = d[0], dy = d[1];
      double dw = d[2] < CLIP_ ? d[2] : CLIP_;
      double dh = d[3] < CLIP_ ? d[3] : CLIP_;
      double pcx = dx * wdt + cx, pcy = dy * hgt + cy;
      double pw = exp(dw) * wdt, ph = exp(dh) * hgt;
      x1 = pcx - 0.5 * pw;
      y1 = pcy - 0.5 * ph;
      x2 = pcx + 0.5 * pw - 1.0;
      y2 = pcy + 0.5 * ph - 1.0;
      double imh = (double)iminfo[b * 3 + 0];
      double imw = (double)iminfo[b * 3 + 1];
      x1 = x1 < 0.0 ? 0.0 : (x1 > imw - 1.0 ? imw - 1.0 : x1);
      y1 = y1 < 0.0 ? 0.0 : (y1 > imh - 1.0 ? imh - 1.0 : y1);
      x2 = x2 < 0.0 ? 0.0 : (x2 > imw - 1.0 ? imw - 1.0 : x2);
      y2 = y2 < 0.0 ? 0.0 : (y2 > imh - 1.0 ? imh - 1.0 : y2);
      double wss = x2 - x1 + 1.0, hss = y2 - y1 + 1.0;
      double xc = x1 + wss / 2.0, yc = y1 + hss / 2.0;
      valid = (wss >= 0.0) && (hss >= 0.0) && (xc < imw) && (yc < imh);
      ar = wss * hss;
    }
    double* bx = boxes + ((size_t)b * NPAD_ + i) * 4;
    bx[0] = x1; bx[1] = y1; bx[2] = x2; bx[3] = y2;
    areas[(size_t)b * NPAD_ + i] = ar;
  }
  u64 bal = __ballot(valid);
  if ((threadIdx.x & 63) == 0) {
    int w = i >> 6;
    if (w < WORDS_) vmask[b * WORDS_ + w] = bal;
  }
}

// ---------------- K6: suppression bitmask v2 (4 row-blocks/block, sparse stores) ----------------
// grid (94 wc, 24 rq, 2 b), 256 threads. mask pre-zeroed by k_init; only nonzero
// words stored. Dead blocks (whole 256-row range at/below the column block) exit
// before the barrier, block-uniformly.
__global__ __launch_bounds__(256) void k_mask(const double* __restrict__ boxes,
                                              const double* __restrict__ areas,
                                              u64* __restrict__ mask) {
#pragma clang fp contract(off)
  const int b = blockIdx.z;
  const int wc = blockIdx.x;        // column word [0,94)
  const int rq = blockIdx.y;        // row quad: rows [rq*256, rq*256+256)
  if (wc * 64 + 63 <= rq * 256) return;  // no j > i anywhere in block (uniform)
  const int i = rq * 256 + (int)threadIdx.x;
  __shared__ double cbx[64][4];
  __shared__ double car[64];
  if (threadIdx.x < 64) {
    int sj = wc * 64 + (int)threadIdx.x;  // <= 6015 < NPAD_
    const double* pj = boxes + ((size_t)b * NPAD_ + sj) * 4;
    cbx[threadIdx.x][0] = pj[0];
    cbx[threadIdx.x][1] = pj[1];
    cbx[threadIdx.x][2] = pj[2];
    cbx[threadIdx.x][3] = pj[3];
    car[threadIdx.x] = areas[(size_t)b * NPAD_ + sj];
  }
  __syncthreads();
  if (i >= PRE_) return;
  int jmax = PRE_ - wc * 64;
  if (jmax > 64) jmax = 64;
  if (wc * 64 + jmax - 1 <= i) return;  // this row has no j > i in the word
  const double* bi = boxes + ((size_t)b * NPAD_ + i) * 4;
  double x1 = bi[0], y1 = bi[1], x2 = bi[2], y2 = bi[3];
  double ai = areas[(size_t)b * NPAD_ + i];
  u64 m = 0;
  for (int j2 = 0; j2 < jmax; ++j2) {
    int j = wc * 64 + j2;
    if (j > i) {
      double ix1 = x1 > cbx[j2][0] ? x1 : cbx[j2][0];
      double iy1 = y1 > cbx[j2][1] ? y1 : cbx[j2][1];
      double ix2 = x2 < cbx[j2][2] ? x2 : cbx[j2][2];
      double iy2 = y2 < cbx[j2][3] ? y2 : cbx[j2][3];
      double iw = ix2 - ix1 + 1.0;
      if (iw < 0.0) iw = 0.0;
      double ih = iy2 - iy1 + 1.0;
      if (ih < 0.0) ih = 0.0;
      double inter = iw * ih;
      double iou = inter / (ai + car[j2] - inter);
      if (iou > NMS_T) m |= (1ull << j2);
    }
  }
  if (m) mask[((size_t)b * NPAD_ + i) * WORDS_ + wc] = m;
}

// ---------------- K7: greedy NMS closure scan (survivor chain, dg prefetch, 4-wide ORs) ----------------
__global__ __launch_bounds__(64) void k_scan(const u64* __restrict__ mask,
                                             const u64* __restrict__ vmask,
                                             u64* __restrict__ keepm) {
  const int b = blockIdx.x;
  const int lane = (int)threadIdx.x;
  u64 rem0 = ~vmask[b * WORDS_ + lane];  // lane holds word `lane` (dead-bits)
  u64 rem1 = (lane < WORDS_ - 64) ? ~vmask[b * WORDS_ + 64 + lane] : ~0ull;
  const u64* mb = mask + (size_t)b * NPAD_ * WORDS_;
  int kept = 0;
  int Bb = 0;
  // prefetch diagonal block 0
  u64 dgnext = (lane < 64) ? mb[(size_t)lane * WORDS_ + 0] : 0ull;
  for (; Bb < WORDS_ && kept < POST_; ++Bb) {
    const int base = Bb * 64;
    int lim = PRE_ - base;
    if (lim > 64) lim = 64;
    u64 dg = (lane < lim) ? dgnext : 0ull;
    // prefetch next diagonal block (latency hides under the serial chain)
    if (Bb + 1 < WORDS_) {
      int nbase = (Bb + 1) * 64;
      int nlim = PRE_ - nbase;
      if (nlim > 64) nlim = 64;
      dgnext = (lane < nlim) ? mb[(size_t)(nbase + lane) * WORDS_ + (Bb + 1)] : 0ull;
    }
    u64 cur = (Bb < 64) ? __shfl(rem0, Bb) : __shfl(rem1, Bb - 64);
    if (lim < 64) cur |= (~0ull) << lim;
    u64 kb = 0;
    while (cur != ~0ull) {
      int t = __ffsll((unsigned long long)~cur) - 1;
      kb |= 1ull << t;
      cur |= __shfl(dg, t);
      cur |= 1ull << t;
      if (++kept >= POST_) break;
    }
    // deferred row-ORs, 4 rows' loads in flight per step (kb is wave-uniform)
    u64 or0 = 0, or1 = 0;
    u64 k2 = kb;
    while (k2) {
      int t0 = __ffsll((unsigned long long)k2) - 1; k2 &= k2 - 1;
      int t1 = -1, t2 = -1, t3 = -1;
      if (k2) { t1 = __ffsll((unsigned long long)k2) - 1; k2 &= k2 - 1; }
      if (k2) { t2 = __ffsll((unsigned long long)k2) - 1; k2 &= k2 - 1; }
      if (k2) { t3 = __ffsll((unsigned long long)k2) - 1; k2 &= k2 - 1; }
      const u64* m0 = mb + (size_t)(base + t0) * WORDS_;
      u64 a0 = m0[lane];
      u64 a1 = (lane < WORDS_ - 64) ? m0[64 + lane] : 0ull;
      u64 b0 = 0, b1 = 0, c0 = 0, c1 = 0, d0 = 0, d1 = 0;
      if (t1 >= 0) {
        const u64* m1 = mb + (size_t)(base + t1) * WORDS_;
        b0 = m1[lane]; b1 = (lane < WORDS_ - 64) ? m1[64 + lane] : 0ull;
      }
      if (t2 >= 0) {
        const u64* m2 = mb + (size_t)(base + t2) * WORDS_;
        c0 = m2[lane]; c1 = (lane < WORDS_ - 64) ? m2[64 + lane] : 0ull;
      }
      if (t3 >= 0) {
        const u64* m3 = mb + (size_t)(base + t3) * WORDS_;
        d0 = m3[lane]; d1 = (lane < WORDS_ - 64) ? m3[64 + lane] : 0ull;
      }
      or0 |= (a0 | b0) | (c0 | d0);
      or1 |= (a1 | b1) | (c1 | d1);
    }
    rem0 |= or0;
    rem1 |= or1;
    if (lane == 0) keepm[b * WORDS_ + Bb] = kb;
  }
  for (int w = Bb + lane; w < WORDS_; w += 64)
    keepm[b * WORDS_ + w] = 0ull;
}

// ---------------- K8: finalize rois + probs (kept in order, then not-kept with -1) ----------------
__global__ __launch_bounds__(256) void k_final(const u64* __restrict__ keepm,
                                               const double* __restrict__ boxes,
                                               const double* __restrict__ ssc,
                                               float* __restrict__ out) {
  const int b = blockIdx.x;
  __shared__ u32 pk[WORDS_ + 1];
  __shared__ u64 km_s[WORDS_];
  for (int w = threadIdx.x; w < WORDS_; w += 256) km_s[w] = keepm[b * WORDS_ + w];
  __syncthreads();
  if (threadIdx.x == 0) {
    u32 a = 0;
    for (int w = 0; w < WORDS_; ++w) {
      pk[w] = a;
      a += (u32)__popcll(km_s[w]);
    }
    pk[WORDS_] = a;
  }
  __syncthreads();
  const u32 K = pk[WORDS_];
  for (int i = threadIdx.x; i < PRE_; i += 256) {
    int w = i >> 6, t = i & 63;
    u64 km = km_s[w];
    u32 before = pk[w] + (u32)__popcll(km & ((1ull << t) - 1ull));
    bool kp = (km >> t) & 1ull;
    int slot = kp ? (int)before : (int)K + (i - (int)before);
    if (slot < POST_) {
      const double* bx = boxes + ((size_t)b * NPAD_ + i) * 4;
      float* ro = out + OUT_ROIS_ + ((size_t)b * POST_ + slot) * 5;
      ro[0] = (float)b;
      ro[1] = (float)bx[0];
      ro[2] = (float)bx[1];
      ro[3] = (float)bx[2];
      ro[4] = (float)bx[3];
      out[OUT_PROBS_ + b * POST_ + slot] = kp ? (float)ssc[(size_t)b * PRE_ + i] : -1.0f;
    }
  }
}

extern "C" void kernel_launch(void* const* d_in, const int* in_sizes, int n_in,
                              void* d_out, int out_size, void* d_ws, size_t ws_size,
                              hipStream_t stream) {
  (void)in_sizes; (void)n_in; (void)out_size; (void)ws_size;
  const float* x = (const float*)d_in[0];
  const float* iminfo = (const float*)d_in[1];
  const float* convw = (const float*)d_in[2];
  const float* convb = (const float*)d_in[3];
  const float* clsw = (const float*)d_in[4];
  const float* clsb = (const float*)d_in[5];
  const float* bbw = (const float*)d_in[6];
  const float* bbb = (const float*)d_in[7];
  const float* anchors = (const float*)d_in[8];
  float* out = (float*)d_out;

  char* ws = (char*)d_ws;
  size_t off = 0;
  auto alloc = [&](size_t bytes) -> void* {
    void* p = ws + off;
    off += (bytes + 255) & ~(size_t)255;
    return p;
  };
  double* wt64 = (double*)alloc((size_t)C_ * 9 * C_ * 8);       // 18.9 MB
  double* h0 = (double*)alloc((size_t)B_ * C_ * HW_ * 8);       // 34.4 MB
  double* h1 = (double*)alloc((size_t)B_ * C_ * HW_ * 8);       // 34.4 MB
  double* scores = (double*)alloc((size_t)B_ * NS_ * 8);        // 1 MB
  double* deltas = (double*)alloc((size_t)B_ * NS_ * 4 * 8);    // 4 MB
  u64* selk = (u64*)alloc((size_t)B_ * SORTN_ * 8);
  u32* seli = (u32*)alloc((size_t)B_ * SORTN_ * 4);
  double* ssc = (double*)alloc((size_t)B_ * PRE_ * 8);
  u32* sidx = (u32*)alloc((size_t)B_ * PRE_ * 4);
  double* boxes = (double*)alloc((size_t)B_ * NPAD_ * 4 * 8);
  double* areas = (double*)alloc((size_t)B_ * NPAD_ * 8);
  u64* vmask = (u64*)alloc((size_t)B_ * WORDS_ * 8);
  u64* mask = (u64*)alloc((size_t)B_ * NPAD_ * WORDS_ * 8);     // 9 MB
  u64* keepm = (u64*)alloc((size_t)B_ * WORDS_ * 8);
  u32* selcnt = (u32*)alloc(2 * 4);
  u32* selhist = (u32*)alloc((size_t)NROUNDS_ * 2 * 256 * 4);

  k_init<<<(B_ * C_ * HW_ + 255) / 256, 256, 0, stream>>>(convw, wt64, h0, h1, mask, selcnt, selhist);
  k_conv3<<<dim3(7, 5, 128), 256, 0, stream>>>(x, wt64, h0, h1);
  k_conv1<<<dim3(132, 2), 256, 0, stream>>>(h0, h1, convb, clsw, clsb, bbw, bbb, out, scores, deltas);
  for (int r = 0; r < NROUNDS_; ++r)
    k_hist<<<dim3(64, 2), 256, 0, stream>>>(scores, selhist, r);
  k_compact<<<dim3(64, 2), 256, 0, stream>>>(scores, selhist, selcnt, selk, seli);
  k_rank<<<dim3(8, 2), 1024, 0, stream>>>(selk, seli, selcnt, ssc, sidx);
  k_decode<<<dim3(24, 2), 256, 0, stream>>>(sidx, deltas, anchors, iminfo, boxes, areas, vmask);
  k_mask<<<dim3(94, 24, 2), 256, 0, stream>>>(boxes, areas, mask);
  k_scan<<<2, 64, 0, stream>>>(mask, vmask, keepm);
  k_final<<<2, 256, 0, stream>>>(keepm, boxes, ssc, out);
}

// Round 14
// 1494.506 us; speedup vs baseline: 1.3376x; 1.2442x over previous
//
#include <hip/hip_runtime.h>
#include <cstdint>
#include <cstddef>

typedef unsigned long long u64;
typedef unsigned int u32;

constexpr int B_ = 2, C_ = 512, H_ = 50, W_ = 84, A_ = 15;
constexpr int HW_ = H_ * W_;        // 4200
constexpr int NS_ = HW_ * A_;       // 63000
constexpr int PRE_ = 6000, POST_ = 1000;
constexpr int WORDS_ = 94;          // ceil(6000/64)
constexpr int NPAD_ = 6016;
constexpr int SORTN_ = 8192;
constexpr double NMS_T = 0.7;
constexpr double CLIP_ = 4.1351665567423556;  // float(np.log(1000/16))
constexpr int OUT_ROIS_ = B_ * A_ * HW_ + B_ * 4 * A_ * HW_;  // 630000
constexpr int OUT_PROBS_ = OUT_ROIS_ + B_ * POST_ * 5;        // 640000
constexpr int NROUNDS_ = 5;

// ---------------- K_init: weight cvt + zero h0/h1, mask, select state, sort padding ----------------
__global__ void k_init(const float* __restrict__ w, double* __restrict__ wt64,
                       double* __restrict__ h0, double* __restrict__ h1,
                       u64* __restrict__ mask, u32* __restrict__ selcnt,
                       u32* __restrict__ selhist, u64* __restrict__ selk,
                       u32* __restrict__ seli) {
  int idx = blockIdx.x * 256 + threadIdx.x;
  if (idx < C_ * C_ * 9) {
    int co = idx & 511;
    int r = idx >> 9;
    int k = r % 9;
    int ci = r / 9;
    wt64[idx] = (double)w[(co * C_ + ci) * 9 + k];
  }
  if (idx < B_ * C_ * HW_) { h0[idx] = 0.0; h1[idx] = 0.0; }
  if (idx < B_ * NPAD_ * WORDS_) mask[idx] = 0ull;
  if (idx < 2) selcnt[idx] = 0u;
  if (idx < NROUNDS_ * 2 * 256) selhist[idx] = 0u;
  if (idx < B_ * SORTN_) { selk[idx] = 0ull; seli[idx] = 0xFFFFFFFFu; }
}

// ---------------- K1: 3x3 conv 512->512, f64, SGPR weights, split-K=4 (R9 proven) ----------------
// block: 256 thr = 4 waves. wave -> 8 co. lane = 12 cols x 5 rowg (60 used).
// grid: (7 colb, 5 rowb, 128 = b*64 + cob*4 + q). Quarters {0,1}->h0, {2,3}->h1:
// each buffer element gets exactly 2 atomicAdds onto 0.0 -> order-independent (IEEE).
__global__ __launch_bounds__(256) void k_conv3(const float* __restrict__ x,
                                               const double* __restrict__ wt64,
                                               double* __restrict__ h0,
                                               double* __restrict__ h1) {
  const int tid = threadIdx.x;
  const int lane = tid & 63;
  const int wid = __builtin_amdgcn_readfirstlane(tid >> 6);  // wave-uniform co group
  const int cg = lane % 12;
  const int rowg = lane / 12;       // 0..4 valid, 5 = idle lane
  const bool act = (rowg < 5);
  const int colb = blockIdx.x;      // 0..6
  const int rowb = blockIdx.y;      // 0..4
  const int z = blockIdx.z;
  const int b = z >> 6;
  const int cob = (z >> 2) & 15;
  const int q = z & 3;
  const int c0 = colb * 12;
  const int rblk = rowb * 10;
  const int col = c0 + cg;
  const int rg5 = act ? rowg : 4;   // clamp idle lanes to safe indices
  const int r0 = rblk + rg5 * 2;
  const int cstart = q * 32;        // cb4 chunk range [cstart, cstart+32)
  double* __restrict__ hp = (q < 2) ? h0 : h1;

  __shared__ double xs[4][14][14];  // [ci][col 12+2halo][row 12 used]

  double acc[2][8];
#pragma unroll
  for (int j = 0; j < 2; ++j)
#pragma unroll
    for (int c = 0; c < 8; ++c) acc[j][c] = 0.0;

  float xreg[3];
  auto loadX = [&](int cb4) {
#pragma unroll
    for (int k = 0; k < 3; ++k) {
      int s = tid + k * 256;
      float v = 0.f;
      if (s < 672) {
        int ci = s / 168;
        int r168 = s % 168;
        int rr = r168 / 14;
        int cc = r168 % 14;
        int gr = rblk - 1 + rr, gc = c0 - 1 + cc;
        if (gr >= 0 && gr < H_ && gc >= 0 && gc < W_)
          v = x[((b * C_ + cb4 * 4 + ci) * H_ + gr) * W_ + gc];
      }
      xreg[k] = v;
    }
  };
  auto storeX = [&]() {
#pragma unroll
    for (int k = 0; k < 3; ++k) {
      int s = tid + k * 256;
      if (s < 672) {
        int ci = s / 168;
        int r168 = s % 168;
        int rr = r168 / 14;
        int cc = r168 % 14;
        xs[ci][cc][rr] = (double)xreg[k];
      }
    }
  };

  // wave-uniform weight base: this wave's 8 output channels
  const double* __restrict__ wb = wt64 + (size_t)(cob * 32 + wid * 8);

  loadX(cstart);
  for (int it = 0; it < 32; ++it) {
    const int cb4 = cstart + it;
    __syncthreads();
    storeX();
    __syncthreads();
    if (it < 31) loadX(cb4 + 1);
#pragma unroll
    for (int ci = 0; ci < 4; ++ci) {
#pragma unroll
      for (int kx = 0; kx < 3; ++kx) {
        double xv[4];
        const double* xp = &xs[ci][cg + kx][rg5 * 2];
#pragma unroll
        for (int t = 0; t < 4; ++t) xv[t] = xp[t];
#pragma unroll
        for (int ky = 0; ky < 3; ++ky) {
          // wave-uniform address -> s_load, values live in SGPR pairs
          const double* __restrict__ wp =
              wb + ((size_t)(cb4 * 4 + ci) * 9 + (ky * 3 + kx)) * C_;
#pragma unroll
          for (int c = 0; c < 8; ++c) {
            double wv = wp[c];
            acc[0][c] = fma(xv[ky], wv, acc[0][c]);
            acc[1][c] = fma(xv[ky + 1], wv, acc[1][c]);
          }
        }
      }
    }
  }

  if (act) {
#pragma unroll
    for (int c = 0; c < 8; ++c) {
      int co = cob * 32 + wid * 8 + c;
#pragma unroll
      for (int j = 0; j < 2; ++j) {
        atomicAdd(&hp[((size_t)b * C_ + co) * HW_ + (r0 + j) * W_ + col], acc[j][c]);
      }
    }
  }
}

// ---------------- K2: 1x1 convs; folds h0+h1, conv bias+ReLU at load ----------------
__global__ __launch_bounds__(256) void k_conv1(const double* __restrict__ h0,
                                               const double* __restrict__ h1,
                                               const float* __restrict__ convb,
                                               const float* __restrict__ clsw,
                                               const float* __restrict__ clsb,
                                               const float* __restrict__ bbw,
                                               const float* __restrict__ bbb,
                                               float* __restrict__ out,
                                               double* __restrict__ scores,
                                               double* __restrict__ deltas) {
  const int b = blockIdx.y;
  const int p0 = blockIdx.x * 32;
  const int tid = threadIdx.x;
  const int px = tid & 31, cg = tid >> 5;  // 8 channel groups, 10 ch each
  __shared__ double hs[64][32];
  __shared__ double wl[64][80];
  double acc[10];
#pragma unroll
  for (int k = 0; k < 10; ++k) acc[k] = 0.0;
  for (int ci0 = 0; ci0 < C_; ci0 += 64) {
    for (int s = tid; s < 64 * 32; s += 256) {
      int ci = s >> 5, pp = s & 31;
      int p = p0 + pp;
      double v = 0.0;
      if (p < HW_) {
        size_t idx = ((size_t)b * C_ + ci0 + ci) * HW_ + p;
        v = (h0[idx] + h1[idx]) + (double)convb[ci0 + ci];
        v = v > 0.0 ? v : 0.0;   // ReLU(conv + bias)
      }
      hs[ci][pp] = v;
    }
    for (int s = tid; s < 64 * 80; s += 256) {
      int ci = s / 80, c = s % 80;
      double v = 0.0;
      if (c < 15) v = (double)clsw[c * C_ + ci0 + ci];
      else if (c < 75) v = (double)bbw[(c - 15) * C_ + ci0 + ci];
      wl[ci][c] = v;
    }
    __syncthreads();
    for (int ci = 0; ci < 64; ++ci) {
      double xv = hs[ci][px];
#pragma unroll
      for (int k = 0; k < 10; ++k)
        acc[k] = fma(wl[ci][cg * 10 + k], xv, acc[k]);
    }
    __syncthreads();
  }
  int p = p0 + px;
  if (p < HW_) {
#pragma unroll
    for (int k = 0; k < 10; ++k) {
      int c = cg * 10 + k;
      if (c < 15) {
        double z = acc[k] + (double)clsb[c];
        out[(size_t)b * NS_ + c * HW_ + p] = (float)z;
        double s = 1.0 / (1.0 + exp(-z));
        scores[(size_t)b * NS_ + (size_t)p * A_ + c] = s;
      } else if (c < 75) {
        int cbx = c - 15;
        double z = acc[k] + (double)bbb[cbx];
        out[(size_t)B_ * NS_ + (size_t)b * (4 * A_ * HW_) + cbx * HW_ + p] = (float)z;
        deltas[(size_t)b * (4 * NS_) + (size_t)p * (4 * A_) + cbx] = z;
      }
    }
  }
}

// ---------------- select: prefix recomputation (deterministic integer scan) ----------------
__device__ inline u64 compute_prefix(const u32* __restrict__ selhist, int b, int rounds) {
  u64 prefix = 0;
  u32 above = 0;
  for (int rr = 0; rr < rounds; ++rr) {
    const u32* h = selhist + (rr * 2 + b) * 256;
    int shift = 56 - 8 * rr;
    u32 c = above;
    int dsel = 0;
    for (int dd = 255; dd >= 0; --dd) {
      u32 nc = c + h[dd];
      if (nc >= (u32)PRE_) { dsel = dd; break; }
      c = nc;
    }
    prefix |= ((u64)dsel << shift);
    above = c;
  }
  return prefix;
}

__global__ __launch_bounds__(256) void k_hist(const double* __restrict__ scores,
                                              u32* __restrict__ selhist, int r) {
  const int b = blockIdx.y;
  const double* sc = scores + (size_t)b * NS_;
  const int lane = (int)(threadIdx.x & 63);
  const int shift = 56 - 8 * r;
  __shared__ u64 sh_prefix;
  if (threadIdx.x == 0) sh_prefix = (r == 0) ? 0ull : compute_prefix(selhist, b, r);
  __syncthreads();
  const u64 prefix = sh_prefix;
  const u64 himask = (r == 0) ? 0ull : (~0ull << (shift + 8));
  u32* hist = selhist + (r * 2 + b) * 256;
  for (int i = blockIdx.x * 256 + (int)threadIdx.x; i < NS_; i += 64 * 256) {
    u64 k = (u64)__double_as_longlong(sc[i]);
    bool valid = ((k & himask) == (prefix & himask));
    u32 d = (u32)((k >> shift) & 255);
    u64 m = __ballot(valid);
#pragma unroll
    for (int bit = 0; bit < 8; ++bit) {
      u64 bb = __ballot((d >> bit) & 1);
      m &= ((d >> bit) & 1) ? bb : ~bb;
    }
    if (valid && lane == (__ffsll((unsigned long long)m) - 1))
      atomicAdd(&hist[d], (u32)__popcll(m));
  }
}

__global__ __launch_bounds__(256) void k_compact(const double* __restrict__ scores,
                                                 const u32* __restrict__ selhist,
                                                 u32* __restrict__ selcnt,
                                                 u64* __restrict__ selk,
                                                 u32* __restrict__ seli) {
  const int b = blockIdx.y;
  const double* sc = scores + (size_t)b * NS_;
  const int lane = (int)(threadIdx.x & 63);
  __shared__ u64 sh_T;
  if (threadIdx.x == 0) sh_T = compute_prefix(selhist, b, NROUNDS_);
  __syncthreads();
  const u64 T = sh_T;
  for (int i = blockIdx.x * 256 + (int)threadIdx.x; i < NS_; i += 64 * 256) {
    u64 k = (u64)__double_as_longlong(sc[i]);
    bool q = (k >= T);
    u64 bal = __ballot(q);
    if (bal) {
      int leader = __ffsll((unsigned long long)bal) - 1;
      u32 wbase = 0;
      if (lane == leader) wbase = atomicAdd(&selcnt[b], (u32)__popcll(bal));
      wbase = (u32)__shfl((int)wbase, leader);
      if (q) {
        u64 below = (lane == 0) ? 0ull : (~0ull >> (64 - lane));
        u32 pos = wbase + (u32)__popcll(bal & below);
        if (pos < (u32)SORTN_) {
          selk[(size_t)b * SORTN_ + pos] = k;
          seli[(size_t)b * SORTN_ + pos] = (u32)i;
        }
      }
    }
  }
}

// ---------------- K4: bitonic sort 8192 (desc by score bits, asc idx) — R9 proven ----------------
__global__ __launch_bounds__(1024) void k_sort(const u64* __restrict__ selk,
                                               const u32* __restrict__ seli,
                                               double* __restrict__ ssc,
                                               u32* __restrict__ sidx) {
  const int b = blockIdx.x;
  __shared__ u64 kk[SORTN_];
  __shared__ u32 vv[SORTN_];
  for (int i = threadIdx.x; i < SORTN_; i += 1024) {
    kk[i] = selk[(size_t)b * SORTN_ + i];
    vv[i] = seli[(size_t)b * SORTN_ + i];
  }
  __syncthreads();
  for (int k = 2; k <= SORTN_; k <<= 1) {
    for (int j = k >> 1; j > 0; j >>= 1) {
      for (int t = threadIdx.x; t < SORTN_; t += 1024) {
        int ixj = t ^ j;
        if (ixj > t) {
          u64 ka = kk[t], kb2 = kk[ixj];
          u32 va = vv[t], vb = vv[ixj];
          bool aBetter = (ka > kb2) || (ka == kb2 && va < vb);
          bool bBetter = (kb2 > ka) || (kb2 == ka && vb < va);
          bool up = (t & k) == 0;           // descending blocks
          bool sw = up ? bBetter : aBetter;
          if (sw) {
            kk[t] = kb2; kk[ixj] = ka;
            vv[t] = vb;  vv[ixj] = va;
          }
        }
      }
      __syncthreads();
    }
  }
  for (int i = threadIdx.x; i < PRE_; i += 1024) {
    ssc[(size_t)b * PRE_ + i] = __longlong_as_double((long long)kk[i]);
    sidx[(size_t)b * PRE_ + i] = vv[i];
  }
}

// ---------------- K5: box decode + clip + valid (f64, contract off) ----------------
__global__ __launch_bounds__(256) void k_decode(const u32* __restrict__ sidx,
                                                const double* __restrict__ deltas,
                                                const float* __restrict__ anchors,
                                                const float* __restrict__ iminfo,
                                                double* __restrict__ boxes,
                                                double* __restrict__ areas,
                                                u64* __restrict__ vmask) {
#pragma clang fp contract(off)
  const int b = blockIdx.y;
  const int i = blockIdx.x * 256 + (int)threadIdx.x;
  bool valid = false;
  if (i < NPAD_) {
    double x1 = 0, y1 = 0, x2 = 0, y2 = 0, ar = 0;
    if (i < PRE_) {
      u32 idx = sidx[(size_t)b * PRE_ + i];
      int p = (int)idx / A_, a = (int)idx % A_;
      int yy = p / W_, xx = p % W_;
      double sx = xx * 16.0, sy = yy * 16.0;
      double b0 = sx + (double)anchors[a * 4 + 0];
      double b1 = sy + (double)anchors[a * 4 + 1];
      double b2 = sx + (double)anchors[a * 4 + 2];
      double b3 = sy + (double)anchors[a * 4 + 3];
      double wdt = b2 - b0 + 1.0, hgt = b3 - b1 + 1.0;
      double cx = b0 + 0.5 * wdt, cy = b1 + 0.5 * hgt;
      const double* d = deltas + (size_t)b * (4 * NS_) + (size_t)idx * 4;
      double dx = d[0], dy = d[1];
      double dw = d[2] < CLIP_ ? d[2] : CLIP_;
      double dh = d[3] < CLIP_ ? d[3] : CLIP_;
      double pcx = dx * wdt + cx, pcy = dy * hgt + cy;
      double pw = exp(dw) * wdt, ph = exp(dh) * hgt;
      x1 = pcx - 0.5 * pw;
      y1 = pcy - 0.5 * ph;
      x2 = pcx + 0.5 * pw - 1.0;
      y2 = pcy + 0.5 * ph - 1.0;
      double imh = (double)iminfo[b * 3 + 0];
      double imw = (double)iminfo[b * 3 + 1];
      x1 = x1 < 0.0 ? 0.0 : (x1 > imw - 1.0 ? imw - 1.0 : x1);
      y1 = y1 < 0.0 ? 0.0 : (y1 > imh - 1.0 ? imh - 1.0 : y1);
      x2 = x2 < 0.0 ? 0.0 : (x2 > imw - 1.0 ? imw - 1.0 : x2);
      y2 = y2 < 0.0 ? 0.0 : (y2 > imh - 1.0 ? imh - 1.0 : y2);
      double wss = x2 - x1 + 1.0, hss = y2 - y1 + 1.0;
      double xc = x1 + wss / 2.0, yc = y1 + hss / 2.0;
      valid = (wss >= 0.0) && (hss >= 0.0) && (xc < imw) && (yc < imh);
      ar = wss * hss;
    }
    double* bx = boxes + ((size_t)b * NPAD_ + i) * 4;
    bx[0] = x1; bx[1] = y1; bx[2] = x2; bx[3] = y2;
    areas[(size_t)b * NPAD_ + i] = ar;
  }
  u64 bal = __ballot(valid);
  if ((threadIdx.x & 63) == 0) {
    int w = i >> 6;
    if (w < WORDS_) vmask[b * WORDS_ + w] = bal;
  }
}

// ---------------- K6: suppression bitmask v2 (4 row-blocks/block, sparse stores) ----------------
__global__ __launch_bounds__(256) void k_mask(const double* __restrict__ boxes,
                                              const double* __restrict__ areas,
                                              u64* __restrict__ mask) {
#pragma clang fp contract(off)
  const int b = blockIdx.z;
  const int wc = blockIdx.x;        // column word [0,94)
  const int rq = blockIdx.y;        // row quad: rows [rq*256, rq*256+256)
  if (wc * 64 + 63 <= rq * 256) return;  // no j > i anywhere in block (uniform)
  const int i = rq * 256 + (int)threadIdx.x;
  __shared__ double cbx[64][4];
  __shared__ double car[64];
  if (threadIdx.x < 64) {
    int sj = wc * 64 + (int)threadIdx.x;  // <= 6015 < NPAD_
    const double* pj = boxes + ((size_t)b * NPAD_ + sj) * 4;
    cbx[threadIdx.x][0] = pj[0];
    cbx[threadIdx.x][1] = pj[1];
    cbx[threadIdx.x][2] = pj[2];
    cbx[threadIdx.x][3] = pj[3];
    car[threadIdx.x] = areas[(size_t)b * NPAD_ + sj];
  }
  __syncthreads();
  if (i >= PRE_) return;
  int jmax = PRE_ - wc * 64;
  if (jmax > 64) jmax = 64;
  if (wc * 64 + jmax - 1 <= i) return;  // this row has no j > i in the word
  const double* bi = boxes + ((size_t)b * NPAD_ + i) * 4;
  double x1 = bi[0], y1 = bi[1], x2 = bi[2], y2 = bi[3];
  double ai = areas[(size_t)b * NPAD_ + i];
  u64 m = 0;
  for (int j2 = 0; j2 < jmax; ++j2) {
    int j = wc * 64 + j2;
    if (j > i) {
      double ix1 = x1 > cbx[j2][0] ? x1 : cbx[j2][0];
      double iy1 = y1 > cbx[j2][1] ? y1 : cbx[j2][1];
      double ix2 = x2 < cbx[j2][2] ? x2 : cbx[j2][2];
      double iy2 = y2 < cbx[j2][3] ? y2 : cbx[j2][3];
      double iw = ix2 - ix1 + 1.0;
      if (iw < 0.0) iw = 0.0;
      double ih = iy2 - iy1 + 1.0;
      if (ih < 0.0) ih = 0.0;
      double inter = iw * ih;
      double iou = inter / (ai + car[j2] - inter);
      if (iou > NMS_T) m |= (1ull << j2);
    }
  }
  if (m) mask[((size_t)b * NPAD_ + i) * WORDS_ + wc] = m;
}

// ---------------- K7: greedy NMS closure scan (survivor chain, dg prefetch, 4-wide ORs) ----------------
__global__ __launch_bounds__(64) void k_scan(const u64* __restrict__ mask,
                                             const u64* __restrict__ vmask,
                                             u64* __restrict__ keepm) {
  const int b = blockIdx.x;
  const int lane = (int)threadIdx.x;
  u64 rem0 = ~vmask[b * WORDS_ + lane];  // lane holds word `lane` (dead-bits)
  u64 rem1 = (lane < WORDS_ - 64) ? ~vmask[b * WORDS_ + 64 + lane] : ~0ull;
  const u64* mb = mask + (size_t)b * NPAD_ * WORDS_;
  int kept = 0;
  int Bb = 0;
  // prefetch diagonal block 0
  u64 dgnext = (lane < 64) ? mb[(size_t)lane * WORDS_ + 0] : 0ull;
  for (; Bb < WORDS_ && kept < POST_; ++Bb) {
    const int base = Bb * 64;
    int lim = PRE_ - base;
    if (lim > 64) lim = 64;
    u64 dg = (lane < lim) ? dgnext : 0ull;
    // prefetch next diagonal block (latency hides under the serial chain)
    if (Bb + 1 < WORDS_) {
      int nbase = (Bb + 1) * 64;
      int nlim = PRE_ - nbase;
      if (nlim > 64) nlim = 64;
      dgnext = (lane < nlim) ? mb[(size_t)(nbase + lane) * WORDS_ + (Bb + 1)] : 0ull;
    }
    u64 cur = (Bb < 64) ? __shfl(rem0, Bb) : __shfl(rem1, Bb - 64);
    if (lim < 64) cur |= (~0ull) << lim;
    u64 kb = 0;
    while (cur != ~0ull) {
      int t = __ffsll((unsigned long long)~cur) - 1;
      kb |= 1ull << t;
      cur |= __shfl(dg, t);
      cur |= 1ull << t;
      if (++kept >= POST_) break;
    }
    // deferred row-ORs, 4 rows' loads in flight per step (kb is wave-uniform)
    u64 or0 = 0, or1 = 0;
    u64 k2 = kb;
    while (k2) {
      int t0 = __ffsll((unsigned long long)k2) - 1; k2 &= k2 - 1;
      int t1 = -1, t2 = -1, t3 = -1;
      if (k2) { t1 = __ffsll((unsigned long long)k2) - 1; k2 &= k2 - 1; }
      if (k2) { t2 = __ffsll((unsigned long long)k2) - 1; k2 &= k2 - 1; }
      if (k2) { t3 = __ffsll((unsigned long long)k2) - 1; k2 &= k2 - 1; }
      const u64* m0 = mb + (size_t)(base + t0) * WORDS_;
      u64 a0 = m0[lane];
      u64 a1 = (lane < WORDS_ - 64) ? m0[64 + lane] : 0ull;
      u64 b0 = 0, b1 = 0, c0 = 0, c1 = 0, d0 = 0, d1 = 0;
      if (t1 >= 0) {
        const u64* m1 = mb + (size_t)(base + t1) * WORDS_;
        b0 = m1[lane]; b1 = (lane < WORDS_ - 64) ? m1[64 + lane] : 0ull;
      }
      if (t2 >= 0) {
        const u64* m2 = mb + (size_t)(base + t2) * WORDS_;
        c0 = m2[lane]; c1 = (lane < WORDS_ - 64) ? m2[64 + lane] : 0ull;
      }
      if (t3 >= 0) {
        const u64* m3 = mb + (size_t)(base + t3) * WORDS_;
        d0 = m3[lane]; d1 = (lane < WORDS_ - 64) ? m3[64 + lane] : 0ull;
      }
      or0 |= (a0 | b0) | (c0 | d0);
      or1 |= (a1 | b1) | (c1 | d1);
    }
    rem0 |= or0;
    rem1 |= or1;
    if (lane == 0) keepm[b * WORDS_ + Bb] = kb;
  }
  for (int w = Bb + lane; w < WORDS_; w += 64)
    keepm[b * WORDS_ + w] = 0ull;
}

// ---------------- K8: finalize rois + probs (kept in order, then not-kept with -1) ----------------
__global__ __launch_bounds__(256) void k_final(const u64* __restrict__ keepm,
                                               const double* __restrict__ boxes,
                                               const double* __restrict__ ssc,
                                               float* __restrict__ out) {
  const int b = blockIdx.x;
  __shared__ u32 pk[WORDS_ + 1];
  __shared__ u64 km_s[WORDS_];
  for (int w = threadIdx.x; w < WORDS_; w += 256) km_s[w] = keepm[b * WORDS_ + w];
  __syncthreads();
  if (threadIdx.x == 0) {
    u32 a = 0;
    for (int w = 0; w < WORDS_; ++w) {
      pk[w] = a;
      a += (u32)__popcll(km_s[w]);
    }
    pk[WORDS_] = a;
  }
  __syncthreads();
  const u32 K = pk[WORDS_];
  for (int i = threadIdx.x; i < PRE_; i += 256) {
    int w = i >> 6, t = i & 63;
    u64 km = km_s[w];
    u32 before = pk[w] + (u32)__popcll(km & ((1ull << t) - 1ull));
    bool kp = (km >> t) & 1ull;
    int slot = kp ? (int)before : (int)K + (i - (int)before);
    if (slot < POST_) {
      const double* bx = boxes + ((size_t)b * NPAD_ + i) * 4;
      float* ro = out + OUT_ROIS_ + ((size_t)b * POST_ + slot) * 5;
      ro[0] = (float)b;
      ro[1] = (float)bx[0];
      ro[2] = (float)bx[1];
      ro[3] = (float)bx[2];
      ro[4] = (float)bx[3];
      out[OUT_PROBS_ + b * POST_ + slot] = kp ? (float)ssc[(size_t)b * PRE_ + i] : -1.0f;
    }
  }
}

extern "C" void kernel_launch(void* const* d_in, const int* in_sizes, int n_in,
                              void* d_out, int out_size, void* d_ws, size_t ws_size,
                              hipStream_t stream) {
  (void)in_sizes; (void)n_in; (void)out_size; (void)ws_size;
  const float* x = (const float*)d_in[0];
  const float* iminfo = (const float*)d_in[1];
  const float* convw = (const float*)d_in[2];
  const float* convb = (const float*)d_in[3];
  const float* clsw = (const float*)d_in[4];
  const float* clsb = (const float*)d_in[5];
  const float* bbw = (const float*)d_in[6];
  const float* bbb = (const float*)d_in[7];
  const float* anchors = (const float*)d_in[8];
  float* out = (float*)d_out;

  char* ws = (char*)d_ws;
  size_t off = 0;
  auto alloc = [&](size_t bytes) -> void* {
    void* p = ws + off;
    off += (bytes + 255) & ~(size_t)255;
    return p;
  };
  double* wt64 = (double*)alloc((size_t)C_ * 9 * C_ * 8);       // 18.9 MB
  double* h0 = (double*)alloc((size_t)B_ * C_ * HW_ * 8);       // 34.4 MB
  double* h1 = (double*)alloc((size_t)B_ * C_ * HW_ * 8);       // 34.4 MB
  double* scores = (double*)alloc((size_t)B_ * NS_ * 8);        // 1 MB
  double* deltas = (double*)alloc((size_t)B_ * NS_ * 4 * 8);    // 4 MB
  u64* selk = (u64*)alloc((size_t)B_ * SORTN_ * 8);
  u32* seli = (u32*)alloc((size_t)B_ * SORTN_ * 4);
  double* ssc = (double*)alloc((size_t)B_ * PRE_ * 8);
  u32* sidx = (u32*)alloc((size_t)B_ * PRE_ * 4);
  double* boxes = (double*)alloc((size_t)B_ * NPAD_ * 4 * 8);
  double* areas = (double*)alloc((size_t)B_ * NPAD_ * 8);
  u64* vmask = (u64*)alloc((size_t)B_ * WORDS_ * 8);
  u64* mask = (u64*)alloc((size_t)B_ * NPAD_ * WORDS_ * 8);     // 9 MB
  u64* keepm = (u64*)alloc((size_t)B_ * WORDS_ * 8);
  u32* selcnt = (u32*)alloc(2 * 4);
  u32* selhist = (u32*)alloc((size_t)NROUNDS_ * 2 * 256 * 4);

  k_init<<<(B_ * C_ * HW_ + 255) / 256, 256, 0, stream>>>(convw, wt64, h0, h1, mask, selcnt, selhist, selk, seli);
  k_conv3<<<dim3(7, 5, 128), 256, 0, stream>>>(x, wt64, h0, h1);
  k_conv1<<<dim3(132, 2), 256, 0, stream>>>(h0, h1, convb, clsw, clsb, bbw, bbb, out, scores, deltas);
  for (int r = 0; r < NROUNDS_; ++r)
    k_hist<<<dim3(64, 2), 256, 0, stream>>>(scores, selhist, r);
  k_compact<<<dim3(64, 2), 256, 0, stream>>>(scores, selhist, selcnt, selk, seli);
  k_sort<<<2, 1024, 0, stream>>>(selk, seli, ssc, sidx);
  k_decode<<<dim3(24, 2), 256, 0, stream>>>(sidx, deltas, anchors, iminfo, boxes, areas, vmask);
  k_mask<<<dim3(94, 24, 2), 256, 0, stream>>>(boxes, areas, mask);
  k_scan<<<2, 64, 0, stream>>>(mask, vmask, keepm);
  k_final<<<2, 256, 0, stream>>>(keepm, boxes, ssc, out);
}

// Round 16
// 1494.466 us; speedup vs baseline: 1.3376x; 1.0000x over previous
//
#include <hip/hip_runtime.h>
#include <cstdint>
#include <cstddef>

typedef unsigned long long u64;
typedef unsigned int u32;

constexpr int B_ = 2, C_ = 512, H_ = 50, W_ = 84, A_ = 15;
constexpr int HW_ = H_ * W_;        // 4200
constexpr int NS_ = HW_ * A_;       // 63000
constexpr int PRE_ = 6000, POST_ = 1000;
constexpr int WORDS_ = 94;          // ceil(6000/64)
constexpr int NPAD_ = 6016;
constexpr int SORTN_ = 8192;
constexpr double NMS_T = 0.7;
constexpr double CLIP_ = 4.1351665567423556;  // float(np.log(1000/16))
constexpr int OUT_ROIS_ = B_ * A_ * HW_ + B_ * 4 * A_ * HW_;  // 630000
constexpr int OUT_PROBS_ = OUT_ROIS_ + B_ * POST_ * 5;        // 640000
constexpr int NROUNDS_ = 5;

// ---------------- K_init: weight cvt + zero h partials, mask, select state, sort padding ----------------
__global__ void k_init(const float* __restrict__ w, double* __restrict__ wt64,
                       double* __restrict__ h0, double* __restrict__ h1,
                       double* __restrict__ h2, double* __restrict__ h3, int nbuf,
                       u64* __restrict__ mask, u32* __restrict__ selcnt,
                       u32* __restrict__ selhist, u64* __restrict__ selk,
                       u32* __restrict__ seli) {
  int idx = blockIdx.x * 256 + threadIdx.x;
  if (idx < C_ * C_ * 9) {
    int co = idx & 511;
    int r = idx >> 9;
    int k = r % 9;
    int ci = r / 9;
    wt64[idx] = (double)w[(co * C_ + ci) * 9 + k];
  }
  if (idx < B_ * C_ * HW_) {
    h0[idx] = 0.0; h1[idx] = 0.0;
    if (nbuf == 4) { h2[idx] = 0.0; h3[idx] = 0.0; }
  }
  if (idx < B_ * NPAD_ * WORDS_) mask[idx] = 0ull;
  if (idx < 2) selcnt[idx] = 0u;
  if (idx < NROUNDS_ * 2 * 256) selhist[idx] = 0u;
  if (idx < B_ * SORTN_) { selk[idx] = 0ull; seli[idx] = 0xFFFFFFFFu; }
}

// ---------------- K1: 3x3 conv 512->512, f64, SGPR weights, split-K = 4 or 8 ----------------
// Inner loop byte-identical to R9/R14 proven body; chunks = 128>>QBITS (compile-time).
// block: 256 thr = 4 waves. wave -> 8 co. lane = 12 cols x 5 rowg (60 used).
// grid: (7 colb, 5 rowb, B*16*(1<<QBITS)); z = b*(16<<QBITS) + cob*(1<<QBITS) + q.
// Buffer index = q>>1: every buffer element gets exactly 2 atomicAdds onto 0.0
// -> order-independent (IEEE).
template<int QBITS>
__global__ __launch_bounds__(256) void k_conv3(const float* __restrict__ x,
                                               const double* __restrict__ wt64,
                                               double* __restrict__ h0,
                                               double* __restrict__ h1,
                                               double* __restrict__ h2,
                                               double* __restrict__ h3) {
  constexpr int CHUNKS = 128 >> QBITS;
  const int tid = threadIdx.x;
  const int lane = tid & 63;
  const int wid = __builtin_amdgcn_readfirstlane(tid >> 6);  // wave-uniform co group
  const int cg = lane % 12;
  const int rowg = lane / 12;       // 0..4 valid, 5 = idle lane
  const bool act = (rowg < 5);
  const int colb = blockIdx.x;      // 0..6
  const int rowb = blockIdx.y;      // 0..4
  const int z = blockIdx.z;
  const int b = z >> (4 + QBITS);
  const int cob = (z >> QBITS) & 15;
  const int q = z & ((1 << QBITS) - 1);
  const int c0 = colb * 12;
  const int rblk = rowb * 10;
  const int col = c0 + cg;
  const int rg5 = act ? rowg : 4;   // clamp idle lanes to safe indices
  const int r0 = rblk + rg5 * 2;
  const int cstart = q * CHUNKS;    // cb4 chunk range
  const int bsel = q >> 1;
  double* __restrict__ hp = (bsel == 0) ? h0 : (bsel == 1) ? h1 : (bsel == 2) ? h2 : h3;

  __shared__ double xs[4][14][14];  // [ci][col 12+2halo][row 12 used]

  double acc[2][8];
#pragma unroll
  for (int j = 0; j < 2; ++j)
#pragma unroll
    for (int c = 0; c < 8; ++c) acc[j][c] = 0.0;

  float xreg[3];
  auto loadX = [&](int cb4) {
#pragma unroll
    for (int k = 0; k < 3; ++k) {
      int s = tid + k * 256;
      float v = 0.f;
      if (s < 672) {
        int ci = s / 168;
        int r168 = s % 168;
        int rr = r168 / 14;
        int cc = r168 % 14;
        int gr = rblk - 1 + rr, gc = c0 - 1 + cc;
        if (gr >= 0 && gr < H_ && gc >= 0 && gc < W_)
          v = x[((b * C_ + cb4 * 4 + ci) * H_ + gr) * W_ + gc];
      }
      xreg[k] = v;
    }
  };
  auto storeX = [&]() {
#pragma unroll
    for (int k = 0; k < 3; ++k) {
      int s = tid + k * 256;
      if (s < 672) {
        int ci = s / 168;
        int r168 = s % 168;
        int rr = r168 / 14;
        int cc = r168 % 14;
        xs[ci][cc][rr] = (double)xreg[k];
      }
    }
  };

  // wave-uniform weight base: this wave's 8 output channels
  const double* __restrict__ wb = wt64 + (size_t)(cob * 32 + wid * 8);

  loadX(cstart);
  for (int it = 0; it < CHUNKS; ++it) {
    const int cb4 = cstart + it;
    __syncthreads();
    storeX();
    __syncthreads();
    if (it < CHUNKS - 1) loadX(cb4 + 1);
#pragma unroll
    for (int ci = 0; ci < 4; ++ci) {
#pragma unroll
      for (int kx = 0; kx < 3; ++kx) {
        double xv[4];
        const double* xp = &xs[ci][cg + kx][rg5 * 2];
#pragma unroll
        for (int t = 0; t < 4; ++t) xv[t] = xp[t];
#pragma unroll
        for (int ky = 0; ky < 3; ++ky) {
          // wave-uniform address -> s_load, values live in SGPR pairs
          const double* __restrict__ wp =
              wb + ((size_t)(cb4 * 4 + ci) * 9 + (ky * 3 + kx)) * C_;
#pragma unroll
          for (int c = 0; c < 8; ++c) {
            double wv = wp[c];
            acc[0][c] = fma(xv[ky], wv, acc[0][c]);
            acc[1][c] = fma(xv[ky + 1], wv, acc[1][c]);
          }
        }
      }
    }
  }

  if (act) {
#pragma unroll
    for (int c = 0; c < 8; ++c) {
      int co = cob * 32 + wid * 8 + c;
#pragma unroll
      for (int j = 0; j < 2; ++j) {
        atomicAdd(&hp[((size_t)b * C_ + co) * HW_ + (r0 + j) * W_ + col], acc[j][c]);
      }
    }
  }
}

// ---------------- K2: 1x1 convs; folds h partials, conv bias+ReLU at load ----------------
__global__ __launch_bounds__(256) void k_conv1(const double* __restrict__ h0,
                                               const double* __restrict__ h1,
                                               const double* __restrict__ h2,
                                               const double* __restrict__ h3, int nbuf,
                                               const float* __restrict__ convb,
                                               const float* __restrict__ clsw,
                                               const float* __restrict__ clsb,
                                               const float* __restrict__ bbw,
                                               const float* __restrict__ bbb,
                                               float* __restrict__ out,
                                               double* __restrict__ scores,
                                               double* __restrict__ deltas) {
  const int b = blockIdx.y;
  const int p0 = blockIdx.x * 32;
  const int tid = threadIdx.x;
  const int px = tid & 31, cg = tid >> 5;  // 8 channel groups, 10 ch each
  __shared__ double hs[64][32];
  __shared__ double wl[64][80];
  double acc[10];
#pragma unroll
  for (int k = 0; k < 10; ++k) acc[k] = 0.0;
  for (int ci0 = 0; ci0 < C_; ci0 += 64) {
    for (int s = tid; s < 64 * 32; s += 256) {
      int ci = s >> 5, pp = s & 31;
      int p = p0 + pp;
      double v = 0.0;
      if (p < HW_) {
        size_t idx = ((size_t)b * C_ + ci0 + ci) * HW_ + p;
        double hsum = h0[idx] + h1[idx];
        if (nbuf == 4) hsum = hsum + (h2[idx] + h3[idx]);
        v = hsum + (double)convb[ci0 + ci];
        v = v > 0.0 ? v : 0.0;   // ReLU(conv + bias)
      }
      hs[ci][pp] = v;
    }
    for (int s = tid; s < 64 * 80; s += 256) {
      int ci = s / 80, c = s % 80;
      double v = 0.0;
      if (c < 15) v = (double)clsw[c * C_ + ci0 + ci];
      else if (c < 75) v = (double)bbw[(c - 15) * C_ + ci0 + ci];
      wl[ci][c] = v;
    }
    __syncthreads();
    for (int ci = 0; ci < 64; ++ci) {
      double xv = hs[ci][px];
#pragma unroll
      for (int k = 0; k < 10; ++k)
        acc[k] = fma(wl[ci][cg * 10 + k], xv, acc[k]);
    }
    __syncthreads();
  }
  int p = p0 + px;
  if (p < HW_) {
#pragma unroll
    for (int k = 0; k < 10; ++k) {
      int c = cg * 10 + k;
      if (c < 15) {
        double z = acc[k] + (double)clsb[c];
        out[(size_t)b * NS_ + c * HW_ + p] = (float)z;
        double s = 1.0 / (1.0 + exp(-z));
        scores[(size_t)b * NS_ + (size_t)p * A_ + c] = s;
      } else if (c < 75) {
        int cbx = c - 15;
        double z = acc[k] + (double)bbb[cbx];
        out[(size_t)B_ * NS_ + (size_t)b * (4 * A_ * HW_) + cbx * HW_ + p] = (float)z;
        deltas[(size_t)b * (4 * NS_) + (size_t)p * (4 * A_) + cbx] = z;
      }
    }
  }
}

// ---------------- select: prefix recomputation (deterministic integer scan) ----------------
__device__ inline u64 compute_prefix(const u32* __restrict__ selhist, int b, int rounds) {
  u64 prefix = 0;
  u32 above = 0;
  for (int rr = 0; rr < rounds; ++rr) {
    const u32* h = selhist + (rr * 2 + b) * 256;
    int shift = 56 - 8 * rr;
    u32 c = above;
    int dsel = 0;
    for (int dd = 255; dd >= 0; --dd) {
      u32 nc = c + h[dd];
      if (nc >= (u32)PRE_) { dsel = dd; break; }
      c = nc;
    }
    prefix |= ((u64)dsel << shift);
    above = c;
  }
  return prefix;
}

__global__ __launch_bounds__(256) void k_hist(const double* __restrict__ scores,
                                              u32* __restrict__ selhist, int r) {
  const int b = blockIdx.y;
  const double* sc = scores + (size_t)b * NS_;
  const int lane = (int)(threadIdx.x & 63);
  const int shift = 56 - 8 * r;
  __shared__ u64 sh_prefix;
  if (threadIdx.x == 0) sh_prefix = (r == 0) ? 0ull : compute_prefix(selhist, b, r);
  __syncthreads();
  const u64 prefix = sh_prefix;
  const u64 himask = (r == 0) ? 0ull : (~0ull << (shift + 8));
  u32* hist = selhist + (r * 2 + b) * 256;
  for (int i = blockIdx.x * 256 + (int)threadIdx.x; i < NS_; i += 64 * 256) {
    u64 k = (u64)__double_as_longlong(sc[i]);
    bool valid = ((k & himask) == (prefix & himask));
    u32 d = (u32)((k >> shift) & 255);
    u64 m = __ballot(valid);
#pragma unroll
    for (int bit = 0; bit < 8; ++bit) {
      u64 bb = __ballot((d >> bit) & 1);
      m &= ((d >> bit) & 1) ? bb : ~bb;
    }
    if (valid && lane == (__ffsll((unsigned long long)m) - 1))
      atomicAdd(&hist[d], (u32)__popcll(m));
  }
}

__global__ __launch_bounds__(256) void k_compact(const double* __restrict__ scores,
                                                 const u32* __restrict__ selhist,
                                                 u32* __restrict__ selcnt,
                                                 u64* __restrict__ selk,
                                                 u32* __restrict__ seli) {
  const int b = blockIdx.y;
  const double* sc = scores + (size_t)b * NS_;
  const int lane = (int)(threadIdx.x & 63);
  __shared__ u64 sh_T;
  if (threadIdx.x == 0) sh_T = compute_prefix(selhist, b, NROUNDS_);
  __syncthreads();
  const u64 T = sh_T;
  for (int i = blockIdx.x * 256 + (int)threadIdx.x; i < NS_; i += 64 * 256) {
    u64 k = (u64)__double_as_longlong(sc[i]);
    bool q = (k >= T);
    u64 bal = __ballot(q);
    if (bal) {
      int leader = __ffsll((unsigned long long)bal) - 1;
      u32 wbase = 0;
      if (lane == leader) wbase = atomicAdd(&selcnt[b], (u32)__popcll(bal));
      wbase = (u32)__shfl((int)wbase, leader);
      if (q) {
        u64 below = (lane == 0) ? 0ull : (~0ull >> (64 - lane));
        u32 pos = wbase + (u32)__popcll(bal & below);
        if (pos < (u32)SORTN_) {
          selk[(size_t)b * SORTN_ + pos] = k;
          seli[(size_t)b * SORTN_ + pos] = (u32)i;
        }
      }
    }
  }
}

// ---------------- K4: bitonic sort 8192 (desc by score bits, asc idx) — R9 proven ----------------
__global__ __launch_bounds__(1024) void k_sort(const u64* __restrict__ selk,
                                               const u32* __restrict__ seli,
                                               double* __restrict__ ssc,
                                               u32* __restrict__ sidx) {
  const int b = blockIdx.x;
  __shared__ u64 kk[SORTN_];
  __shared__ u32 vv[SORTN_];
  for (int i = threadIdx.x; i < SORTN_; i += 1024) {
    kk[i] = selk[(size_t)b * SORTN_ + i];
    vv[i] = seli[(size_t)b * SORTN_ + i];
  }
  __syncthreads();
  for (int k = 2; k <= SORTN_; k <<= 1) {
    for (int j = k >> 1; j > 0; j >>= 1) {
      for (int t = threadIdx.x; t < SORTN_; t += 1024) {
        int ixj = t ^ j;
        if (ixj > t) {
          u64 ka = kk[t], kb2 = kk[ixj];
          u32 va = vv[t], vb = vv[ixj];
          bool aBetter = (ka > kb2) || (ka == kb2 && va < vb);
          bool bBetter = (kb2 > ka) || (kb2 == ka && vb < va);
          bool up = (t & k) == 0;           // descending blocks
          bool sw = up ? bBetter : aBetter;
          if (sw) {
            kk[t] = kb2; kk[ixj] = ka;
            vv[t] = vb;  vv[ixj] = va;
          }
        }
      }
      __syncthreads();
    }
  }
  for (int i = threadIdx.x; i < PRE_; i += 1024) {
    ssc[(size_t)b * PRE_ + i] = __longlong_as_double((long long)kk[i]);
    sidx[(size_t)b * PRE_ + i] = vv[i];
  }
}

// ---------------- K5: box decode + clip + valid (f64, contract off) ----------------
__global__ __launch_bounds__(256) void k_decode(const u32* __restrict__ sidx,
                                                const double* __restrict__ deltas,
                                                const float* __restrict__ anchors,
                                                const float* __restrict__ iminfo,
                                                double* __restrict__ boxes,
                                                double* __restrict__ areas,
                                                u64* __restrict__ vmask) {
#pragma clang fp contract(off)
  const int b = blockIdx.y;
  const int i = blockIdx.x * 256 + (int)threadIdx.x;
  bool valid = false;
  if (i < NPAD_) {
    double x1 = 0, y1 = 0, x2 = 0, y2 = 0, ar = 0;
    if (i < PRE_) {
      u32 idx = sidx[(size_t)b * PRE_ + i];
      int p = (int)idx / A_, a = (int)idx % A_;
      int yy = p / W_, xx = p % W_;
      double sx = xx * 16.0, sy = yy * 16.0;
      double b0 = sx + (double)anchors[a * 4 + 0];
      double b1 = sy + (double)anchors[a * 4 + 1];
      double b2 = sx + (double)anchors[a * 4 + 2];
      double b3 = sy + (double)anchors[a * 4 + 3];
      double wdt = b2 - b0 + 1.0, hgt = b3 - b1 + 1.0;
      double cx = b0 + 0.5 * wdt, cy = b1 + 0.5 * hgt;
      const double* d = deltas + (size_t)b * (4 * NS_) + (size_t)idx * 4;
      double dx = d[0], dy = d[1];
      double dw = d[2] < CLIP_ ? d[2] : CLIP_;
      double dh = d[3] < CLIP_ ? d[3] : CLIP_;
      double pcx = dx * wdt + cx, pcy = dy * hgt + cy;
      double pw = exp(dw) * wdt, ph = exp(dh) * hgt;
      x1 = pcx - 0.5 * pw;
      y1 = pcy - 0.5 * ph;
      x2 = pcx + 0.5 * pw - 1.0;
      y2 = pcy + 0.5 * ph - 1.0;
      double imh = (double)iminfo[b * 3 + 0];
      double imw = (double)iminfo[b * 3 + 1];
      x1 = x1 < 0.0 ? 0.0 : (x1 > imw - 1.0 ? imw - 1.0 : x1);
      y1 = y1 < 0.0 ? 0.0 : (y1 > imh - 1.0 ? imh - 1.0 : y1);
      x2 = x2 < 0.0 ? 0.0 : (x2 > imw - 1.0 ? imw - 1.0 : x2);
      y2 = y2 < 0.0 ? 0.0 : (y2 > imh - 1.0 ? imh - 1.0 : y2);
      double wss = x2 - x1 + 1.0, hss = y2 - y1 + 1.0;
      double xc = x1 + wss / 2.0, yc = y1 + hss / 2.0;
      valid = (wss >= 0.0) && (hss >= 0.0) && (xc < imw) && (yc < imh);
      ar = wss * hss;
    }
    double* bx = boxes + ((size_t)b * NPAD_ + i) * 4;
    bx[0] = x1; bx[1] = y1; bx[2] = x2; bx[3] = y2;
    areas[(size_t)b * NPAD_ + i] = ar;
  }
  u64 bal = __ballot(valid);
  if ((threadIdx.x & 63) == 0) {
    int w = i >> 6;
    if (w < WORDS_) vmask[b * WORDS_ + w] = bal;
  }
}

// ---------------- K6: suppression bitmask v2 (4 row-blocks/block, sparse stores) ----------------
__global__ __launch_bounds__(256) void k_mask(const double* __restrict__ boxes,
                                              const double* __restrict__ areas,
                                              u64* __restrict__ mask) {
#pragma clang fp contract(off)
  const int b = blockIdx.z;
  const int wc = blockIdx.x;        // column word [0,94)
  const int rq = blockIdx.y;        // row quad: rows [rq*256, rq*256+256)
  if (wc * 64 + 63 <= rq * 256) return;  // no j > i anywhere in block (uniform)
  const int i = rq * 256 + (int)threadIdx.x;
  __shared__ double cbx[64][4];
  __shared__ double car[64];
  if (threadIdx.x < 64) {
    int sj = wc * 64 + (int)threadIdx.x;  // <= 6015 < NPAD_
    const double* pj = boxes + ((size_t)b * NPAD_ + sj) * 4;
    cbx[threadIdx.x][0] = pj[0];
    cbx[threadIdx.x][1] = pj[1];
    cbx[threadIdx.x][2] = pj[2];
    cbx[threadIdx.x][3] = pj[3];
    car[threadIdx.x] = areas[(size_t)b * NPAD_ + sj];
  }
  __syncthreads();
  if (i >= PRE_) return;
  int jmax = PRE_ - wc * 64;
  if (jmax > 64) jmax = 64;
  if (wc * 64 + jmax - 1 <= i) return;  // this row has no j > i in the word
  const double* bi = boxes + ((size_t)b * NPAD_ + i) * 4;
  double x1 = bi[0], y1 = bi[1], x2 = bi[2], y2 = bi[3];
  double ai = areas[(size_t)b * NPAD_ + i];
  u64 m = 0;
  for (int j2 = 0; j2 < jmax; ++j2) {
    int j = wc * 64 + j2;
    if (j > i) {
      double ix1 = x1 > cbx[j2][0] ? x1 : cbx[j2][0];
      double iy1 = y1 > cbx[j2][1] ? y1 : cbx[j2][1];
      double ix2 = x2 < cbx[j2][2] ? x2 : cbx[j2][2];
      double iy2 = y2 < cbx[j2][3] ? y2 : cbx[j2][3];
      double iw = ix2 - ix1 + 1.0;
      if (iw < 0.0) iw = 0.0;
      double ih = iy2 - iy1 + 1.0;
      if (ih < 0.0) ih = 0.0;
      double inter = iw * ih;
      double iou = inter / (ai + car[j2] - inter);
      if (iou > NMS_T) m |= (1ull << j2);
    }
  }
  if (m) mask[((size_t)b * NPAD_ + i) * WORDS_ + wc] = m;
}

// ---------------- K7: greedy NMS closure scan (survivor chain, dg prefetch, 4-wide ORs) ----------------
__global__ __launch_bounds__(64) void k_scan(const u64* __restrict__ mask,
                                             const u64* __restrict__ vmask,
                                             u64* __restrict__ keepm) {
  const int b = blockIdx.x;
  const int lane = (int)threadIdx.x;
  u64 rem0 = ~vmask[b * WORDS_ + lane];  // lane holds word `lane` (dead-bits)
  u64 rem1 = (lane < WORDS_ - 64) ? ~vmask[b * WORDS_ + 64 + lane] : ~0ull;
  const u64* mb = mask + (size_t)b * NPAD_ * WORDS_;
  int kept = 0;
  int Bb = 0;
  // prefetch diagonal block 0
  u64 dgnext = (lane < 64) ? mb[(size_t)lane * WORDS_ + 0] : 0ull;
  for (; Bb < WORDS_ && kept < POST_; ++Bb) {
    const int base = Bb * 64;
    int lim = PRE_ - base;
    if (lim > 64) lim = 64;
    u64 dg = (lane < lim) ? dgnext : 0ull;
    // prefetch next diagonal block (latency hides under the serial chain)
    if (Bb + 1 < WORDS_) {
      int nbase = (Bb + 1) * 64;
      int nlim = PRE_ - nbase;
      if (nlim > 64) nlim = 64;
      dgnext = (lane < nlim) ? mb[(size_t)(nbase + lane) * WORDS_ + (Bb + 1)] : 0ull;
    }
    u64 cur = (Bb < 64) ? __shfl(rem0, Bb) : __shfl(rem1, Bb - 64);
    if (lim < 64) cur |= (~0ull) << lim;
    u64 kb = 0;
    while (cur != ~0ull) {
      int t = __ffsll((unsigned long long)~cur) - 1;
      kb |= 1ull << t;
      cur |= __shfl(dg, t);
      cur |= 1ull << t;
      if (++kept >= POST_) break;
    }
    // deferred row-ORs, 4 rows' loads in flight per step (kb is wave-uniform)
    u64 or0 = 0, or1 = 0;
    u64 k2 = kb;
    while (k2) {
      int t0 = __ffsll((unsigned long long)k2) - 1; k2 &= k2 - 1;
      int t1 = -1, t2 = -1, t3 = -1;
      if (k2) { t1 = __ffsll((unsigned long long)k2) - 1; k2 &= k2 - 1; }
      if (k2) { t2 = __ffsll((unsigned long long)k2) - 1; k2 &= k2 - 1; }
      if (k2) { t3 = __ffsll((unsigned long long)k2) - 1; k2 &= k2 - 1; }
      const u64* m0 = mb + (size_t)(base + t0) * WORDS_;
      u64 a0 = m0[lane];
      u64 a1 = (lane < WORDS_ - 64) ? m0[64 + lane] : 0ull;
      u64 b0 = 0, b1 = 0, c0 = 0, c1 = 0, d0 = 0, d1 = 0;
      if (t1 >= 0) {
        const u64* m1 = mb + (size_t)(base + t1) * WORDS_;
        b0 = m1[lane]; b1 = (lane < WORDS_ - 64) ? m1[64 + lane] : 0ull;
      }
      if (t2 >= 0) {
        const u64* m2 = mb + (size_t)(base + t2) * WORDS_;
        c0 = m2[lane]; c1 = (lane < WORDS_ - 64) ? m2[64 + lane] : 0ull;
      }
      if (t3 >= 0) {
        const u64* m3 = mb + (size_t)(base + t3) * WORDS_;
        d0 = m3[lane]; d1 = (lane < WORDS_ - 64) ? m3[64 + lane] : 0ull;
      }
      or0 |= (a0 | b0) | (c0 | d0);
      or1 |= (a1 | b1) | (c1 | d1);
    }
    rem0 |= or0;
    rem1 |= or1;
    if (lane == 0) keepm[b * WORDS_ + Bb] = kb;
  }
  for (int w = Bb + lane; w < WORDS_; w += 64)
    keepm[b * WORDS_ + w] = 0ull;
}

// ---------------- K8: finalize rois + probs (kept in order, then not-kept with -1) ----------------
__global__ __launch_bounds__(256) void k_final(const u64* __restrict__ keepm,
                                               const double* __restrict__ boxes,
                                               const double* __restrict__ ssc,
                                               float* __restrict__ out) {
  const int b = blockIdx.x;
  __shared__ u32 pk[WORDS_ + 1];
  __shared__ u64 km_s[WORDS_];
  for (int w = threadIdx.x; w < WORDS_; w += 256) km_s[w] = keepm[b * WORDS_ + w];
  __syncthreads();
  if (threadIdx.x == 0) {
    u32 a = 0;
    for (int w = 0; w < WORDS_; ++w) {
      pk[w] = a;
      a += (u32)__popcll(km_s[w]);
    }
    pk[WORDS_] = a;
  }
  __syncthreads();
  const u32 K = pk[WORDS_];
  for (int i = threadIdx.x; i < PRE_; i += 256) {
    int w = i >> 6, t = i & 63;
    u64 km = km_s[w];
    u32 before = pk[w] + (u32)__popcll(km & ((1ull << t) - 1ull));
    bool kp = (km >> t) & 1ull;
    int slot = kp ? (int)before : (int)K + (i - (int)before);
    if (slot < POST_) {
      const double* bx = boxes + ((size_t)b * NPAD_ + i) * 4;
      float* ro = out + OUT_ROIS_ + ((size_t)b * POST_ + slot) * 5;
      ro[0] = (float)b;
      ro[1] = (float)bx[0];
      ro[2] = (float)bx[1];
      ro[3] = (float)bx[2];
      ro[4] = (float)bx[3];
      out[OUT_PROBS_ + b * POST_ + slot] = kp ? (float)ssc[(size_t)b * PRE_ + i] : -1.0f;
    }
  }
}

extern "C" void kernel_launch(void* const* d_in, const int* in_sizes, int n_in,
                              void* d_out, int out_size, void* d_ws, size_t ws_size,
                              hipStream_t stream) {
  (void)in_sizes; (void)n_in; (void)out_size;
  const float* x = (const float*)d_in[0];
  const float* iminfo = (const float*)d_in[1];
  const float* convw = (const float*)d_in[2];
  const float* convb = (const float*)d_in[3];
  const float* clsw = (const float*)d_in[4];
  const float* clsb = (const float*)d_in[5];
  const float* bbw = (const float*)d_in[6];
  const float* bbb = (const float*)d_in[7];
  const float* anchors = (const float*)d_in[8];
  float* out = (float*)d_out;

  char* ws = (char*)d_ws;
  size_t off = 0;
  auto alloc = [&](size_t bytes) -> void* {
    void* p = ws + off;
    off += (bytes + 255) & ~(size_t)255;
    return p;
  };
  const size_t HB = (size_t)B_ * C_ * HW_ * 8;                  // 34.4 MB
  double* wt64 = (double*)alloc((size_t)C_ * 9 * C_ * 8);       // 18.9 MB
  double* h0 = (double*)alloc(HB);
  double* h1 = (double*)alloc(HB);
  double* scores = (double*)alloc((size_t)B_ * NS_ * 8);        // 1 MB
  double* deltas = (double*)alloc((size_t)B_ * NS_ * 4 * 8);    // 4 MB
  u64* selk = (u64*)alloc((size_t)B_ * SORTN_ * 8);
  u32* seli = (u32*)alloc((size_t)B_ * SORTN_ * 4);
  double* ssc = (double*)alloc((size_t)B_ * PRE_ * 8);
  u32* sidx = (u32*)alloc((size_t)B_ * PRE_ * 4);
  double* boxes = (double*)alloc((size_t)B_ * NPAD_ * 4 * 8);
  double* areas = (double*)alloc((size_t)B_ * NPAD_ * 8);
  u64* vmask = (u64*)alloc((size_t)B_ * WORDS_ * 8);
  u64* mask = (u64*)alloc((size_t)B_ * NPAD_ * WORDS_ * 8);     // 9 MB
  u64* keepm = (u64*)alloc((size_t)B_ * WORDS_ * 8);
  u32* selcnt = (u32*)alloc(2 * 4);
  u32* selhist = (u32*)alloc((size_t)NROUNDS_ * 2 * 256 * 4);

  // split-K=8 needs 2 extra partial buffers; fall back to proven split-K=4 if
  // the workspace is too small (decision depends only on ws_size: deterministic).
  const bool k8 = (ws_size >= off + 2 * (HB + 256) + 256);
  double* h2 = h0;
  double* h3 = h1;
  int nbuf = 2;
  if (k8) {
    h2 = (double*)alloc(HB);
    h3 = (double*)alloc(HB);
    nbuf = 4;
  }

  k_init<<<(B_ * C_ * HW_ + 255) / 256, 256, 0, stream>>>(
      convw, wt64, h0, h1, h2, h3, nbuf, mask, selcnt, selhist, selk, seli);
  if (k8)
    k_conv3<3><<<dim3(7, 5, 256), 256, 0, stream>>>(x, wt64, h0, h1, h2, h3);
  else
    k_conv3<2><<<dim3(7, 5, 128), 256, 0, stream>>>(x, wt64, h0, h1, h2, h3);
  k_conv1<<<dim3(132, 2), 256, 0, stream>>>(h0, h1, h2, h3, nbuf, convb, clsw, clsb,
                                            bbw, bbb, out, scores, deltas);
  for (int r = 0; r < NROUNDS_; ++r)
    k_hist<<<dim3(64, 2), 256, 0, stream>>>(scores, selhist, r);
  k_compact<<<dim3(64, 2), 256, 0, stream>>>(scores, selhist, selcnt, selk, seli);
  k_sort<<<2, 1024, 0, stream>>>(selk, seli, ssc, sidx);
  k_decode<<<dim3(24, 2), 256, 0, stream>>>(sidx, deltas, anchors, iminfo, boxes, areas, vmask);
  k_mask<<<dim3(94, 24, 2), 256, 0, stream>>>(boxes, areas, mask);
  k_scan<<<2, 64, 0, stream>>>(mask, vmask, keepm);
  k_final<<<2, 256, 0, stream>>>(keepm, boxes, ssc, out);
}

// Round 17
// 1385.069 us; speedup vs baseline: 1.4432x; 1.0790x over previous
//
#include <hip/hip_runtime.h>
#include <cstdint>
#include <cstddef>

typedef unsigned long long u64;
typedef unsigned int u32;

constexpr int B_ = 2, C_ = 512, H_ = 50, W_ = 84, A_ = 15;
constexpr int HW_ = H_ * W_;        // 4200
constexpr int NS_ = HW_ * A_;       // 63000
constexpr int PRE_ = 6000, POST_ = 1000;
constexpr int WORDS_ = 94;          // ceil(6000/64)
constexpr int NPAD_ = 6016;
constexpr int SORTN_ = 8192;
constexpr double NMS_T = 0.7;
constexpr double CLIP_ = 4.1351665567423556;  // float(np.log(1000/16))
constexpr int OUT_ROIS_ = B_ * A_ * HW_ + B_ * 4 * A_ * HW_;  // 630000
constexpr int OUT_PROBS_ = OUT_ROIS_ + B_ * POST_ * 5;        // 640000
constexpr int NROUNDS_ = 5;
constexpr int JCH_ = 8;             // j-chunks for distributed rank

// ---------------- K_init: weight cvt + zero h partials, mask, select/rank state ----------------
__global__ void k_init(const float* __restrict__ w, double* __restrict__ wt64,
                       double* __restrict__ h0, double* __restrict__ h1,
                       double* __restrict__ h2, double* __restrict__ h3, int nbuf,
                       u64* __restrict__ mask, u32* __restrict__ selcnt,
                       u32* __restrict__ selhist, u32* __restrict__ rankb) {
  int idx = blockIdx.x * 256 + threadIdx.x;
  if (idx < C_ * C_ * 9) {
    int co = idx & 511;
    int r = idx >> 9;
    int k = r % 9;
    int ci = r / 9;
    wt64[idx] = (double)w[(co * C_ + ci) * 9 + k];
  }
  if (idx < B_ * C_ * HW_) {
    h0[idx] = 0.0; h1[idx] = 0.0;
    if (nbuf == 4) { h2[idx] = 0.0; h3[idx] = 0.0; }
  }
  if (idx < B_ * NPAD_ * WORDS_) mask[idx] = 0ull;
  if (idx < 2) selcnt[idx] = 0u;
  if (idx < NROUNDS_ * 2 * 256) selhist[idx] = 0u;
  if (idx < B_ * SORTN_) rankb[idx] = 0u;
}

// ---------------- K1: 3x3 conv 512->512, f64, SGPR weights, split-K = 4 or 8 ----------------
// Inner loop byte-identical to R9/R14 proven body; chunks = 128>>QBITS (compile-time).
// block: 256 thr = 4 waves. wave -> 8 co. lane = 12 cols x 5 rowg (60 used).
// grid: (7 colb, 5 rowb, B*16*(1<<QBITS)); z = b*(16<<QBITS) + cob*(1<<QBITS) + q.
// Buffer index = q>>1: every buffer element gets exactly 2 atomicAdds onto 0.0
// -> order-independent (IEEE).
template<int QBITS>
__global__ __launch_bounds__(256) void k_conv3(const float* __restrict__ x,
                                               const double* __restrict__ wt64,
                                               double* __restrict__ h0,
                                               double* __restrict__ h1,
                                               double* __restrict__ h2,
                                               double* __restrict__ h3) {
  constexpr int CHUNKS = 128 >> QBITS;
  const int tid = threadIdx.x;
  const int lane = tid & 63;
  const int wid = __builtin_amdgcn_readfirstlane(tid >> 6);  // wave-uniform co group
  const int cg = lane % 12;
  const int rowg = lane / 12;       // 0..4 valid, 5 = idle lane
  const bool act = (rowg < 5);
  const int colb = blockIdx.x;      // 0..6
  const int rowb = blockIdx.y;      // 0..4
  const int z = blockIdx.z;
  const int b = z >> (4 + QBITS);
  const int cob = (z >> QBITS) & 15;
  const int q = z & ((1 << QBITS) - 1);
  const int c0 = colb * 12;
  const int rblk = rowb * 10;
  const int col = c0 + cg;
  const int rg5 = act ? rowg : 4;   // clamp idle lanes to safe indices
  const int r0 = rblk + rg5 * 2;
  const int cstart = q * CHUNKS;    // cb4 chunk range
  const int bsel = q >> 1;
  double* __restrict__ hp = (bsel == 0) ? h0 : (bsel == 1) ? h1 : (bsel == 2) ? h2 : h3;

  __shared__ double xs[4][14][14];  // [ci][col 12+2halo][row 12 used]

  double acc[2][8];
#pragma unroll
  for (int j = 0; j < 2; ++j)
#pragma unroll
    for (int c = 0; c < 8; ++c) acc[j][c] = 0.0;

  float xreg[3];
  auto loadX = [&](int cb4) {
#pragma unroll
    for (int k = 0; k < 3; ++k) {
      int s = tid + k * 256;
      float v = 0.f;
      if (s < 672) {
        int ci = s / 168;
        int r168 = s % 168;
        int rr = r168 / 14;
        int cc = r168 % 14;
        int gr = rblk - 1 + rr, gc = c0 - 1 + cc;
        if (gr >= 0 && gr < H_ && gc >= 0 && gc < W_)
          v = x[((b * C_ + cb4 * 4 + ci) * H_ + gr) * W_ + gc];
      }
      xreg[k] = v;
    }
  };
  auto storeX = [&]() {
#pragma unroll
    for (int k = 0; k < 3; ++k) {
      int s = tid + k * 256;
      if (s < 672) {
        int ci = s / 168;
        int r168 = s % 168;
        int rr = r168 / 14;
        int cc = r168 % 14;
        xs[ci][cc][rr] = (double)xreg[k];
      }
    }
  };

  // wave-uniform weight base: this wave's 8 output channels
  const double* __restrict__ wb = wt64 + (size_t)(cob * 32 + wid * 8);

  loadX(cstart);
  for (int it = 0; it < CHUNKS; ++it) {
    const int cb4 = cstart + it;
    __syncthreads();
    storeX();
    __syncthreads();
    if (it < CHUNKS - 1) loadX(cb4 + 1);
#pragma unroll
    for (int ci = 0; ci < 4; ++ci) {
#pragma unroll
      for (int kx = 0; kx < 3; ++kx) {
        double xv[4];
        const double* xp = &xs[ci][cg + kx][rg5 * 2];
#pragma unroll
        for (int t = 0; t < 4; ++t) xv[t] = xp[t];
#pragma unroll
        for (int ky = 0; ky < 3; ++ky) {
          // wave-uniform address -> s_load, values live in SGPR pairs
          const double* __restrict__ wp =
              wb + ((size_t)(cb4 * 4 + ci) * 9 + (ky * 3 + kx)) * C_;
#pragma unroll
          for (int c = 0; c < 8; ++c) {
            double wv = wp[c];
            acc[0][c] = fma(xv[ky], wv, acc[0][c]);
            acc[1][c] = fma(xv[ky + 1], wv, acc[1][c]);
          }
        }
      }
    }
  }

  if (act) {
#pragma unroll
    for (int c = 0; c < 8; ++c) {
      int co = cob * 32 + wid * 8 + c;
#pragma unroll
      for (int j = 0; j < 2; ++j) {
        atomicAdd(&hp[((size_t)b * C_ + co) * HW_ + (r0 + j) * W_ + col], acc[j][c]);
      }
    }
  }
}

// ---------------- K2: 1x1 convs; folds h partials, conv bias+ReLU at load ----------------
__global__ __launch_bounds__(256) void k_conv1(const double* __restrict__ h0,
                                               const double* __restrict__ h1,
                                               const double* __restrict__ h2,
                                               const double* __restrict__ h3, int nbuf,
                                               const float* __restrict__ convb,
                                               const float* __restrict__ clsw,
                                               const float* __restrict__ clsb,
                                               const float* __restrict__ bbw,
                                               const float* __restrict__ bbb,
                                               float* __restrict__ out,
                                               double* __restrict__ scores,
                                               double* __restrict__ deltas) {
  const int b = blockIdx.y;
  const int p0 = blockIdx.x * 32;
  const int tid = threadIdx.x;
  const int px = tid & 31, cg = tid >> 5;  // 8 channel groups, 10 ch each
  __shared__ double hs[64][32];
  __shared__ double wl[64][80];
  double acc[10];
#pragma unroll
  for (int k = 0; k < 10; ++k) acc[k] = 0.0;
  for (int ci0 = 0; ci0 < C_; ci0 += 64) {
    for (int s = tid; s < 64 * 32; s += 256) {
      int ci = s >> 5, pp = s & 31;
      int p = p0 + pp;
      double v = 0.0;
      if (p < HW_) {
        size_t idx = ((size_t)b * C_ + ci0 + ci) * HW_ + p;
        double hsum = h0[idx] + h1[idx];
        if (nbuf == 4) hsum = hsum + (h2[idx] + h3[idx]);
        v = hsum + (double)convb[ci0 + ci];
        v = v > 0.0 ? v : 0.0;   // ReLU(conv + bias)
      }
      hs[ci][pp] = v;
    }
    for (int s = tid; s < 64 * 80; s += 256) {
      int ci = s / 80, c = s % 80;
      double v = 0.0;
      if (c < 15) v = (double)clsw[c * C_ + ci0 + ci];
      else if (c < 75) v = (double)bbw[(c - 15) * C_ + ci0 + ci];
      wl[ci][c] = v;
    }
    __syncthreads();
    for (int ci = 0; ci < 64; ++ci) {
      double xv = hs[ci][px];
#pragma unroll
      for (int k = 0; k < 10; ++k)
        acc[k] = fma(wl[ci][cg * 10 + k], xv, acc[k]);
    }
    __syncthreads();
  }
  int p = p0 + px;
  if (p < HW_) {
#pragma unroll
    for (int k = 0; k < 10; ++k) {
      int c = cg * 10 + k;
      if (c < 15) {
        double z = acc[k] + (double)clsb[c];
        out[(size_t)b * NS_ + c * HW_ + p] = (float)z;
        double s = 1.0 / (1.0 + exp(-z));
        scores[(size_t)b * NS_ + (size_t)p * A_ + c] = s;
      } else if (c < 75) {
        int cbx = c - 15;
        double z = acc[k] + (double)bbb[cbx];
        out[(size_t)B_ * NS_ + (size_t)b * (4 * A_ * HW_) + cbx * HW_ + p] = (float)z;
        deltas[(size_t)b * (4 * NS_) + (size_t)p * (4 * A_) + cbx] = z;
      }
    }
  }
}

// ---------------- select: prefix recomputation (deterministic integer scan) ----------------
__device__ inline u64 compute_prefix(const u32* __restrict__ selhist, int b, int rounds) {
  u64 prefix = 0;
  u32 above = 0;
  for (int rr = 0; rr < rounds; ++rr) {
    const u32* h = selhist + (rr * 2 + b) * 256;
    int shift = 56 - 8 * rr;
    u32 c = above;
    int dsel = 0;
    for (int dd = 255; dd >= 0; --dd) {
      u32 nc = c + h[dd];
      if (nc >= (u32)PRE_) { dsel = dd; break; }
      c = nc;
    }
    prefix |= ((u64)dsel << shift);
    above = c;
  }
  return prefix;
}

__global__ __launch_bounds__(256) void k_hist(const double* __restrict__ scores,
                                              u32* __restrict__ selhist, int r) {
  const int b = blockIdx.y;
  const double* sc = scores + (size_t)b * NS_;
  const int lane = (int)(threadIdx.x & 63);
  const int shift = 56 - 8 * r;
  __shared__ u64 sh_prefix;
  if (threadIdx.x == 0) sh_prefix = (r == 0) ? 0ull : compute_prefix(selhist, b, r);
  __syncthreads();
  const u64 prefix = sh_prefix;
  const u64 himask = (r == 0) ? 0ull : (~0ull << (shift + 8));
  u32* hist = selhist + (r * 2 + b) * 256;
  for (int i = blockIdx.x * 256 + (int)threadIdx.x; i < NS_; i += 64 * 256) {
    u64 k = (u64)__double_as_longlong(sc[i]);
    bool valid = ((k & himask) == (prefix & himask));
    u32 d = (u32)((k >> shift) & 255);
    u64 m = __ballot(valid);
#pragma unroll
    for (int bit = 0; bit < 8; ++bit) {
      u64 bb = __ballot((d >> bit) & 1);
      m &= ((d >> bit) & 1) ? bb : ~bb;
    }
    if (valid && lane == (__ffsll((unsigned long long)m) - 1))
      atomicAdd(&hist[d], (u32)__popcll(m));
  }
}

__global__ __launch_bounds__(256) void k_compact(const double* __restrict__ scores,
                                                 const u32* __restrict__ selhist,
                                                 u32* __restrict__ selcnt,
                                                 u64* __restrict__ selk,
                                                 u32* __restrict__ seli) {
  const int b = blockIdx.y;
  const double* sc = scores + (size_t)b * NS_;
  const int lane = (int)(threadIdx.x & 63);
  __shared__ u64 sh_T;
  if (threadIdx.x == 0) sh_T = compute_prefix(selhist, b, NROUNDS_);
  __syncthreads();
  const u64 T = sh_T;
  for (int i = blockIdx.x * 256 + (int)threadIdx.x; i < NS_; i += 64 * 256) {
    u64 k = (u64)__double_as_longlong(sc[i]);
    bool q = (k >= T);
    u64 bal = __ballot(q);
    if (bal) {
      int leader = __ffsll((unsigned long long)bal) - 1;
      u32 wbase = 0;
      if (lane == leader) wbase = atomicAdd(&selcnt[b], (u32)__popcll(bal));
      wbase = (u32)__shfl((int)wbase, leader);
      if (q) {
        u64 below = (lane == 0) ? 0ull : (~0ull >> (64 - lane));
        u32 pos = wbase + (u32)__popcll(bal & below);
        if (pos < (u32)SORTN_) {
          selk[(size_t)b * SORTN_ + pos] = k;
          seli[(size_t)b * SORTN_ + pos] = (u32)i;
        }
      }
    }
  }
}

// ---------------- K4a: distributed rank count (desc by key, asc idx) ----------------
// grid (8 e-blocks, JCH_ j-chunks, B). Each block counts, for its 1024 owners e,
// how many candidates in its j-chunk outrank e; integer atomicAdd accumulation is
// order-independent -> deterministic. 128 blocks spread the ~36-49M comparisons
// across the chip (the R13 k_rank put them on 16 CUs - that was the 3x regression).
__global__ __launch_bounds__(1024) void k_rankcnt(const u64* __restrict__ selk,
                                                  const u32* __restrict__ seli,
                                                  const u32* __restrict__ selcnt,
                                                  u32* __restrict__ rankb) {
  const int b = blockIdx.z;
  int mn = (int)selcnt[b];
  if (mn > SORTN_) mn = SORTN_;
  const int e = blockIdx.x * 1024 + (int)threadIdx.x;
  const bool active = (e < mn);
  u64 ke = 0; u32 ie = 0;
  if (active) {
    ke = selk[(size_t)b * SORTN_ + e];
    ie = seli[(size_t)b * SORTN_ + e];
  }
  const int jlen = (mn + JCH_ - 1) / JCH_;
  const int j0 = blockIdx.y * jlen;
  int j1 = j0 + jlen;
  if (j1 > mn) j1 = mn;
  __shared__ u64 ks[1024];
  __shared__ u32 isx[1024];
  u32 cnt = 0;
  for (int t0 = j0; t0 < j1; t0 += 1024) {
    int j = t0 + (int)threadIdx.x;
    if (j < j1) {
      ks[threadIdx.x] = selk[(size_t)b * SORTN_ + j];
      isx[threadIdx.x] = seli[(size_t)b * SORTN_ + j];
    }
    __syncthreads();
    int lim = j1 - t0;
    if (lim > 1024) lim = 1024;
    if (active) {
      for (int jj = 0; jj < lim; ++jj) {
        u64 kj = ks[jj];
        bool better = (kj > ke) || (kj == ke && isx[jj] < ie);
        cnt += better ? 1u : 0u;
      }
    }
    __syncthreads();
  }
  if (active && cnt) atomicAdd(&rankb[b * SORTN_ + e], cnt);
}

// ---------------- K4b: scatter by rank (ranks are a permutation of [0,mn)) ----------------
__global__ __launch_bounds__(256) void k_scatter(const u64* __restrict__ selk,
                                                 const u32* __restrict__ seli,
                                                 const u32* __restrict__ selcnt,
                                                 const u32* __restrict__ rankb,
                                                 double* __restrict__ ssc,
                                                 u32* __restrict__ sidx) {
  const int b = blockIdx.y;
  int mn = (int)selcnt[b];
  if (mn > SORTN_) mn = SORTN_;
  int e = blockIdx.x * 256 + (int)threadIdx.x;
  if (e < mn) {
    u32 r = rankb[b * SORTN_ + e];
    if (r < (u32)PRE_) {
      ssc[(size_t)b * PRE_ + r] = __longlong_as_double((long long)selk[(size_t)b * SORTN_ + e]);
      sidx[(size_t)b * PRE_ + r] = seli[(size_t)b * SORTN_ + e];
    }
  }
}

// ---------------- K5: box decode + clip + valid (f64, contract off) ----------------
__global__ __launch_bounds__(256) void k_decode(const u32* __restrict__ sidx,
                                                const double* __restrict__ deltas,
                                                const float* __restrict__ anchors,
                                                const float* __restrict__ iminfo,
                                                double* __restrict__ boxes,
                                                double* __restrict__ areas,
                                                u64* __restrict__ vmask) {
#pragma clang fp contract(off)
  const int b = blockIdx.y;
  const int i = blockIdx.x * 256 + (int)threadIdx.x;
  bool valid = false;
  if (i < NPAD_) {
    double x1 = 0, y1 = 0, x2 = 0, y2 = 0, ar = 0;
    if (i < PRE_) {
      u32 idx = sidx[(size_t)b * PRE_ + i];
      int p = (int)idx / A_, a = (int)idx % A_;
      int yy = p / W_, xx = p % W_;
      double sx = xx * 16.0, sy = yy * 16.0;
      double b0 = sx + (double)anchors[a * 4 + 0];
      double b1 = sy + (double)anchors[a * 4 + 1];
      double b2 = sx + (double)anchors[a * 4 + 2];
      double b3 = sy + (double)anchors[a * 4 + 3];
      double wdt = b2 - b0 + 1.0, hgt = b3 - b1 + 1.0;
      double cx = b0 + 0.5 * wdt, cy = b1 + 0.5 * hgt;
      const double* d = deltas + (size_t)b * (4 * NS_) + (size_t)idx * 4;
      double dx = d[0], dy = d[1];
      double dw = d[2] < CLIP_ ? d[2] : CLIP_;
      double dh = d[3] < CLIP_ ? d[3] : CLIP_;
      double pcx = dx * wdt + cx, pcy = dy * hgt + cy;
      double pw = exp(dw) * wdt, ph = exp(dh) * hgt;
      x1 = pcx - 0.5 * pw;
      y1 = pcy - 0.5 * ph;
      x2 = pcx + 0.5 * pw - 1.0;
      y2 = pcy + 0.5 * ph - 1.0;
      double imh = (double)iminfo[b * 3 + 0];
      double imw = (double)iminfo[b * 3 + 1];
      x1 = x1 < 0.0 ? 0.0 : (x1 > imw - 1.0 ? imw - 1.0 : x1);
      y1 = y1 < 0.0 ? 0.0 : (y1 > imh - 1.0 ? imh - 1.0 : y1);
      x2 = x2 < 0.0 ? 0.0 : (x2 > imw - 1.0 ? imw - 1.0 : x2);
      y2 = y2 < 0.0 ? 0.0 : (y2 > imh - 1.0 ? imh - 1.0 : y2);
      double wss = x2 - x1 + 1.0, hss = y2 - y1 + 1.0;
      double xc = x1 + wss / 2.0, yc = y1 + hss / 2.0;
      valid = (wss >= 0.0) && (hss >= 0.0) && (xc < imw) && (yc < imh);
      ar = wss * hss;
    }
    double* bx = boxes + ((size_t)b * NPAD_ + i) * 4;
    bx[0] = x1; bx[1] = y1; bx[2] = x2; bx[3] = y2;
    areas[(size_t)b * NPAD_ + i] = ar;
  }
  u64 bal = __ballot(valid);
  if ((threadIdx.x & 63) == 0) {
    int w = i >> 6;
    if (w < WORDS_) vmask[b * WORDS_ + w] = bal;
  }
}

// ---------------- K6: suppression bitmask v2 (4 row-blocks/block, sparse stores) ----------------
__global__ __launch_bounds__(256) void k_mask(const double* __restrict__ boxes,
                                              const double* __restrict__ areas,
                                              u64* __restrict__ mask) {
#pragma clang fp contract(off)
  const int b = blockIdx.z;
  const int wc = blockIdx.x;        // column word [0,94)
  const int rq = blockIdx.y;        // row quad: rows [rq*256, rq*256+256)
  if (wc * 64 + 63 <= rq * 256) return;  // no j > i anywhere in block (uniform)
  const int i = rq * 256 + (int)threadIdx.x;
  __shared__ double cbx[64][4];
  __shared__ double car[64];
  if (threadIdx.x < 64) {
    int sj = wc * 64 + (int)threadIdx.x;  // <= 6015 < NPAD_
    const double* pj = boxes + ((size_t)b * NPAD_ + sj) * 4;
    cbx[threadIdx.x][0] = pj[0];
    cbx[threadIdx.x][1] = pj[1];
    cbx[threadIdx.x][2] = pj[2];
    cbx[threadIdx.x][3] = pj[3];
    car[threadIdx.x] = areas[(size_t)b * NPAD_ + sj];
  }
  __syncthreads();
  if (i >= PRE_) return;
  int jmax = PRE_ - wc * 64;
  if (jmax > 64) jmax = 64;
  if (wc * 64 + jmax - 1 <= i) return;  // this row has no j > i in the word
  const double* bi = boxes + ((size_t)b * NPAD_ + i) * 4;
  double x1 = bi[0], y1 = bi[1], x2 = bi[2], y2 = bi[3];
  double ai = areas[(size_t)b * NPAD_ + i];
  u64 m = 0;
  for (int j2 = 0; j2 < jmax; ++j2) {
    int j = wc * 64 + j2;
    if (j > i) {
      double ix1 = x1 > cbx[j2][0] ? x1 : cbx[j2][0];
      double iy1 = y1 > cbx[j2][1] ? y1 : cbx[j2][1];
      double ix2 = x2 < cbx[j2][2] ? x2 : cbx[j2][2];
      double iy2 = y2 < cbx[j2][3] ? y2 : cbx[j2][3];
      double iw = ix2 - ix1 + 1.0;
      if (iw < 0.0) iw = 0.0;
      double ih = iy2 - iy1 + 1.0;
      if (ih < 0.0) ih = 0.0;
      double inter = iw * ih;
      double iou = inter / (ai + car[j2] - inter);
      if (iou > NMS_T) m |= (1ull << j2);
    }
  }
  if (m) mask[((size_t)b * NPAD_ + i) * WORDS_ + wc] = m;
}

// ---------------- K7: greedy NMS closure scan (survivor chain, dg prefetch, 4-wide ORs) ----------------
__global__ __launch_bounds__(64) void k_scan(const u64* __restrict__ mask,
                                             const u64* __restrict__ vmask,
                                             u64* __restrict__ keepm) {
  const int b = blockIdx.x;
  const int lane = (int)threadIdx.x;
  u64 rem0 = ~vmask[b * WORDS_ + lane];  // lane holds word `lane` (dead-bits)
  u64 rem1 = (lane < WORDS_ - 64) ? ~vmask[b * WORDS_ + 64 + lane] : ~0ull;
  const u64* mb = mask + (size_t)b * NPAD_ * WORDS_;
  int kept = 0;
  int Bb = 0;
  // prefetch diagonal block 0
  u64 dgnext = (lane < 64) ? mb[(size_t)lane * WORDS_ + 0] : 0ull;
  for (; Bb < WORDS_ && kept < POST_; ++Bb) {
    const int base = Bb * 64;
    int lim = PRE_ - base;
    if (lim > 64) lim = 64;
    u64 dg = (lane < lim) ? dgnext : 0ull;
    // prefetch next diagonal block (latency hides under the serial chain)
    if (Bb + 1 < WORDS_) {
      int nbase = (Bb + 1) * 64;
      int nlim = PRE_ - nbase;
      if (nlim > 64) nlim = 64;
      dgnext = (lane < nlim) ? mb[(size_t)(nbase + lane) * WORDS_ + (Bb + 1)] : 0ull;
    }
    u64 cur = (Bb < 64) ? __shfl(rem0, Bb) : __shfl(rem1, Bb - 64);
    if (lim < 64) cur |= (~0ull) << lim;
    u64 kb = 0;
    while (cur != ~0ull) {
      int t = __ffsll((unsigned long long)~cur) - 1;
      kb |= 1ull << t;
      cur |= __shfl(dg, t);
      cur |= 1ull << t;
      if (++kept >= POST_) break;
    }
    // deferred row-ORs, 4 rows' loads in flight per step (kb is wave-uniform)
    u64 or0 = 0, or1 = 0;
    u64 k2 = kb;
    while (k2) {
      int t0 = __ffsll((unsigned long long)k2) - 1; k2 &= k2 - 1;
      int t1 = -1, t2 = -1, t3 = -1;
      if (k2) { t1 = __ffsll((unsigned long long)k2) - 1; k2 &= k2 - 1; }
      if (k2) { t2 = __ffsll((unsigned long long)k2) - 1; k2 &= k2 - 1; }
      if (k2) { t3 = __ffsll((unsigned long long)k2) - 1; k2 &= k2 - 1; }
      const u64* m0 = mb + (size_t)(base + t0) * WORDS_;
      u64 a0 = m0[lane];
      u64 a1 = (lane < WORDS_ - 64) ? m0[64 + lane] : 0ull;
      u64 b0 = 0, b1 = 0, c0 = 0, c1 = 0, d0 = 0, d1 = 0;
      if (t1 >= 0) {
        const u64* m1 = mb + (size_t)(base + t1) * WORDS_;
        b0 = m1[lane]; b1 = (lane < WORDS_ - 64) ? m1[64 + lane] : 0ull;
      }
      if (t2 >= 0) {
        const u64* m2 = mb + (size_t)(base + t2) * WORDS_;
        c0 = m2[lane]; c1 = (lane < WORDS_ - 64) ? m2[64 + lane] : 0ull;
      }
      if (t3 >= 0) {
        const u64* m3 = mb + (size_t)(base + t3) * WORDS_;
        d0 = m3[lane]; d1 = (lane < WORDS_ - 64) ? m3[64 + lane] : 0ull;
      }
      or0 |= (a0 | b0) | (c0 | d0);
      or1 |= (a1 | b1) | (c1 | d1);
    }
    rem0 |= or0;
    rem1 |= or1;
    if (lane == 0) keepm[b * WORDS_ + Bb] = kb;
  }
  for (int w = Bb + lane; w < WORDS_; w += 64)
    keepm[b * WORDS_ + w] = 0ull;
}

// ---------------- K8: finalize rois + probs (kept in order, then not-kept with -1) ----------------
__global__ __launch_bounds__(256) void k_final(const u64* __restrict__ keepm,
                                               const double* __restrict__ boxes,
                                               const double* __restrict__ ssc,
                                               float* __restrict__ out) {
  const int b = blockIdx.x;
  __shared__ u32 pk[WORDS_ + 1];
  __shared__ u64 km_s[WORDS_];
  for (int w = threadIdx.x; w < WORDS_; w += 256) km_s[w] = keepm[b * WORDS_ + w];
  __syncthreads();
  if (threadIdx.x == 0) {
    u32 a = 0;
    for (int w = 0; w < WORDS_; ++w) {
      pk[w] = a;
      a += (u32)__popcll(km_s[w]);
    }
    pk[WORDS_] = a;
  }
  __syncthreads();
  const u32 K = pk[WORDS_];
  for (int i = threadIdx.x; i < PRE_; i += 256) {
    int w = i >> 6, t = i & 63;
    u64 km = km_s[w];
    u32 before = pk[w] + (u32)__popcll(km & ((1ull << t) - 1ull));
    bool kp = (km >> t) & 1ull;
    int slot = kp ? (int)before : (int)K + (i - (int)before);
    if (slot < POST_) {
      const double* bx = boxes + ((size_t)b * NPAD_ + i) * 4;
      float* ro = out + OUT_ROIS_ + ((size_t)b * POST_ + slot) * 5;
      ro[0] = (float)b;
      ro[1] = (float)bx[0];
      ro[2] = (float)bx[1];
      ro[3] = (float)bx[2];
      ro[4] = (float)bx[3];
      out[OUT_PROBS_ + b * POST_ + slot] = kp ? (float)ssc[(size_t)b * PRE_ + i] : -1.0f;
    }
  }
}

extern "C" void kernel_launch(void* const* d_in, const int* in_sizes, int n_in,
                              void* d_out, int out_size, void* d_ws, size_t ws_size,
                              hipStream_t stream) {
  (void)in_sizes; (void)n_in; (void)out_size;
  const float* x = (const float*)d_in[0];
  const float* iminfo = (const float*)d_in[1];
  const float* convw = (const float*)d_in[2];
  const float* convb = (const float*)d_in[3];
  const float* clsw = (const float*)d_in[4];
  const float* clsb = (const float*)d_in[5];
  const float* bbw = (const float*)d_in[6];
  const float* bbb = (const float*)d_in[7];
  const float* anchors = (const float*)d_in[8];
  float* out = (float*)d_out;

  char* ws = (char*)d_ws;
  size_t off = 0;
  auto alloc = [&](size_t bytes) -> void* {
    void* p = ws + off;
    off += (bytes + 255) & ~(size_t)255;
    return p;
  };
  const size_t HB = (size_t)B_ * C_ * HW_ * 8;                  // 34.4 MB
  double* wt64 = (double*)alloc((size_t)C_ * 9 * C_ * 8);       // 18.9 MB
  double* h0 = (double*)alloc(HB);
  double* h1 = (double*)alloc(HB);
  double* scores = (double*)alloc((size_t)B_ * NS_ * 8);        // 1 MB
  double* deltas = (double*)alloc((size_t)B_ * NS_ * 4 * 8);    // 4 MB
  u64* selk = (u64*)alloc((size_t)B_ * SORTN_ * 8);
  u32* seli = (u32*)alloc((size_t)B_ * SORTN_ * 4);
  double* ssc = (double*)alloc((size_t)B_ * PRE_ * 8);
  u32* sidx = (u32*)alloc((size_t)B_ * PRE_ * 4);
  double* boxes = (double*)alloc((size_t)B_ * NPAD_ * 4 * 8);
  double* areas = (double*)alloc((size_t)B_ * NPAD_ * 8);
  u64* vmask = (u64*)alloc((size_t)B_ * WORDS_ * 8);
  u64* mask = (u64*)alloc((size_t)B_ * NPAD_ * WORDS_ * 8);     // 9 MB
  u64* keepm = (u64*)alloc((size_t)B_ * WORDS_ * 8);
  u32* selcnt = (u32*)alloc(2 * 4);
  u32* selhist = (u32*)alloc((size_t)NROUNDS_ * 2 * 256 * 4);
  u32* rankb = (u32*)alloc((size_t)B_ * SORTN_ * 4);

  // split-K=8 needs 2 extra partial buffers; fall back to proven split-K=4 if
  // the workspace is too small (decision depends only on ws_size: deterministic).
  const bool k8 = (ws_size >= off + 2 * (HB + 256) + 256);
  double* h2 = h0;
  double* h3 = h1;
  int nbuf = 2;
  if (k8) {
    h2 = (double*)alloc(HB);
    h3 = (double*)alloc(HB);
    nbuf = 4;
  }

  k_init<<<(B_ * C_ * HW_ + 255) / 256, 256, 0, stream>>>(
      convw, wt64, h0, h1, h2, h3, nbuf, mask, selcnt, selhist, rankb);
  if (k8)
    k_conv3<3><<<dim3(7, 5, 256), 256, 0, stream>>>(x, wt64, h0, h1, h2, h3);
  else
    k_conv3<2><<<dim3(7, 5, 128), 256, 0, stream>>>(x, wt64, h0, h1, h2, h3);
  k_conv1<<<dim3(132, 2), 256, 0, stream>>>(h0, h1, h2, h3, nbuf, convb, clsw, clsb,
                                            bbw, bbb, out, scores, deltas);
  for (int r = 0; r < NROUNDS_; ++r)
    k_hist<<<dim3(64, 2), 256, 0, stream>>>(scores, selhist, r);
  k_compact<<<dim3(64, 2), 256, 0, stream>>>(scores, selhist, selcnt, selk, seli);
  k_rankcnt<<<dim3(8, JCH_, 2), 1024, 0, stream>>>(selk, seli, selcnt, rankb);
  k_scatter<<<dim3(32, 2), 256, 0, stream>>>(selk, seli, selcnt, rankb, ssc, sidx);
  k_decode<<<dim3(24, 2), 256, 0, stream>>>(sidx, deltas, anchors, iminfo, boxes, areas, vmask);
  k_mask<<<dim3(94, 24, 2), 256, 0, stream>>>(boxes, areas, mask);
  k_scan<<<2, 64, 0, stream>>>(mask, vmask, keepm);
  k_final<<<2, 256, 0, stream>>>(keepm, boxes, ssc, out);
}

// Round 18
// 1357.221 us; speedup vs baseline: 1.4729x; 1.0205x over previous
//
#include <hip/hip_runtime.h>
#include <cstdint>
#include <cstddef>

typedef unsigned long long u64;
typedef unsigned int u32;

constexpr int B_ = 2, C_ = 512, H_ = 50, W_ = 84, A_ = 15;
constexpr int HW_ = H_ * W_;        // 4200
constexpr int NS_ = HW_ * A_;       // 63000
constexpr int PRE_ = 6000, POST_ = 1000;
constexpr int WORDS_ = 94;          // ceil(6000/64)
constexpr int NPAD_ = 6016;
constexpr int SORTN_ = 8192;
constexpr double NMS_T = 0.7;
constexpr double CLIP_ = 4.1351665567423556;  // float(np.log(1000/16))
constexpr int OUT_ROIS_ = B_ * A_ * HW_ + B_ * 4 * A_ * HW_;  // 630000
constexpr int OUT_PROBS_ = OUT_ROIS_ + B_ * POST_ * 5;        // 640000
constexpr int NROUNDS_ = 5;
constexpr int JCH_ = 16;            // j-chunks for distributed rank

// ---------------- K_init: weight cvt + zero h partials, mask, select/rank state ----------------
__global__ void k_init(const float* __restrict__ w, double* __restrict__ wt64,
                       double* __restrict__ h0, double* __restrict__ h1,
                       double* __restrict__ h2, double* __restrict__ h3, int nbuf,
                       u64* __restrict__ mask, u32* __restrict__ selcnt,
                       u32* __restrict__ selhist, u32* __restrict__ rankb) {
  int idx = blockIdx.x * 256 + threadIdx.x;
  if (idx < C_ * C_ * 9) {
    int co = idx & 511;
    int r = idx >> 9;
    int k = r % 9;
    int ci = r / 9;
    wt64[idx] = (double)w[(co * C_ + ci) * 9 + k];
  }
  if (idx < B_ * C_ * HW_) {
    h0[idx] = 0.0; h1[idx] = 0.0;
    if (nbuf == 4) { h2[idx] = 0.0; h3[idx] = 0.0; }
  }
  if (idx < B_ * NPAD_ * WORDS_) mask[idx] = 0ull;
  if (idx < 2) selcnt[idx] = 0u;
  if (idx < NROUNDS_ * 2 * 256) selhist[idx] = 0u;
  if (idx < B_ * SORTN_) rankb[idx] = 0u;
}

// ---------------- K1: 3x3 conv 512->512, f64, SGPR weights, split-K = 4 or 8 ----------------
// Inner loop byte-identical to R9/R14 proven body; chunks = 128>>QBITS (compile-time).
// block: 256 thr = 4 waves. wave -> 8 co. lane = 12 cols x 5 rowg (60 used).
// grid: (7 colb, 5 rowb, B*16*(1<<QBITS)); z = b*(16<<QBITS) + cob*(1<<QBITS) + q.
// Buffer index = q>>1: every buffer element gets exactly 2 atomicAdds onto 0.0
// -> order-independent (IEEE).
template<int QBITS>
__global__ __launch_bounds__(256) void k_conv3(const float* __restrict__ x,
                                               const double* __restrict__ wt64,
                                               double* __restrict__ h0,
                                               double* __restrict__ h1,
                                               double* __restrict__ h2,
                                               double* __restrict__ h3) {
  constexpr int CHUNKS = 128 >> QBITS;
  const int tid = threadIdx.x;
  const int lane = tid & 63;
  const int wid = __builtin_amdgcn_readfirstlane(tid >> 6);  // wave-uniform co group
  const int cg = lane % 12;
  const int rowg = lane / 12;       // 0..4 valid, 5 = idle lane
  const bool act = (rowg < 5);
  const int colb = blockIdx.x;      // 0..6
  const int rowb = blockIdx.y;      // 0..4
  const int z = blockIdx.z;
  const int b = z >> (4 + QBITS);
  const int cob = (z >> QBITS) & 15;
  const int q = z & ((1 << QBITS) - 1);
  const int c0 = colb * 12;
  const int rblk = rowb * 10;
  const int col = c0 + cg;
  const int rg5 = act ? rowg : 4;   // clamp idle lanes to safe indices
  const int r0 = rblk + rg5 * 2;
  const int cstart = q * CHUNKS;    // cb4 chunk range
  const int bsel = q >> 1;
  double* __restrict__ hp = (bsel == 0) ? h0 : (bsel == 1) ? h1 : (bsel == 2) ? h2 : h3;

  __shared__ double xs[4][14][14];  // [ci][col 12+2halo][row 12 used]

  double acc[2][8];
#pragma unroll
  for (int j = 0; j < 2; ++j)
#pragma unroll
    for (int c = 0; c < 8; ++c) acc[j][c] = 0.0;

  float xreg[3];
  auto loadX = [&](int cb4) {
#pragma unroll
    for (int k = 0; k < 3; ++k) {
      int s = tid + k * 256;
      float v = 0.f;
      if (s < 672) {
        int ci = s / 168;
        int r168 = s % 168;
        int rr = r168 / 14;
        int cc = r168 % 14;
        int gr = rblk - 1 + rr, gc = c0 - 1 + cc;
        if (gr >= 0 && gr < H_ && gc >= 0 && gc < W_)
          v = x[((b * C_ + cb4 * 4 + ci) * H_ + gr) * W_ + gc];
      }
      xreg[k] = v;
    }
  };
  auto storeX = [&]() {
#pragma unroll
    for (int k = 0; k < 3; ++k) {
      int s = tid + k * 256;
      if (s < 672) {
        int ci = s / 168;
        int r168 = s % 168;
        int rr = r168 / 14;
        int cc = r168 % 14;
        xs[ci][cc][rr] = (double)xreg[k];
      }
    }
  };

  // wave-uniform weight base: this wave's 8 output channels
  const double* __restrict__ wb = wt64 + (size_t)(cob * 32 + wid * 8);

  loadX(cstart);
  for (int it = 0; it < CHUNKS; ++it) {
    const int cb4 = cstart + it;
    __syncthreads();
    storeX();
    __syncthreads();
    if (it < CHUNKS - 1) loadX(cb4 + 1);
#pragma unroll
    for (int ci = 0; ci < 4; ++ci) {
#pragma unroll
      for (int kx = 0; kx < 3; ++kx) {
        double xv[4];
        const double* xp = &xs[ci][cg + kx][rg5 * 2];
#pragma unroll
        for (int t = 0; t < 4; ++t) xv[t] = xp[t];
#pragma unroll
        for (int ky = 0; ky < 3; ++ky) {
          // wave-uniform address -> s_load, values live in SGPR pairs
          const double* __restrict__ wp =
              wb + ((size_t)(cb4 * 4 + ci) * 9 + (ky * 3 + kx)) * C_;
#pragma unroll
          for (int c = 0; c < 8; ++c) {
            double wv = wp[c];
            acc[0][c] = fma(xv[ky], wv, acc[0][c]);
            acc[1][c] = fma(xv[ky + 1], wv, acc[1][c]);
          }
        }
      }
    }
  }

  if (act) {
#pragma unroll
    for (int c = 0; c < 8; ++c) {
      int co = cob * 32 + wid * 8 + c;
#pragma unroll
      for (int j = 0; j < 2; ++j) {
        atomicAdd(&hp[((size_t)b * C_ + co) * HW_ + (r0 + j) * W_ + col], acc[j][c]);
      }
    }
  }
}

// ---------------- K2: 1x1 convs; folds h partials, conv bias+ReLU at load ----------------
__global__ __launch_bounds__(256) void k_conv1(const double* __restrict__ h0,
                                               const double* __restrict__ h1,
                                               const double* __restrict__ h2,
                                               const double* __restrict__ h3, int nbuf,
                                               const float* __restrict__ convb,
                                               const float* __restrict__ clsw,
                                               const float* __restrict__ clsb,
                                               const float* __restrict__ bbw,
                                               const float* __restrict__ bbb,
                                               float* __restrict__ out,
                                               double* __restrict__ scores,
                                               double* __restrict__ deltas) {
  const int b = blockIdx.y;
  const int p0 = blockIdx.x * 32;
  const int tid = threadIdx.x;
  const int px = tid & 31, cg = tid >> 5;  // 8 channel groups, 10 ch each
  __shared__ double hs[64][32];
  __shared__ double wl[64][80];
  double acc[10];
#pragma unroll
  for (int k = 0; k < 10; ++k) acc[k] = 0.0;
  for (int ci0 = 0; ci0 < C_; ci0 += 64) {
    for (int s = tid; s < 64 * 32; s += 256) {
      int ci = s >> 5, pp = s & 31;
      int p = p0 + pp;
      double v = 0.0;
      if (p < HW_) {
        size_t idx = ((size_t)b * C_ + ci0 + ci) * HW_ + p;
        double hsum = h0[idx] + h1[idx];
        if (nbuf == 4) hsum = hsum + (h2[idx] + h3[idx]);
        v = hsum + (double)convb[ci0 + ci];
        v = v > 0.0 ? v : 0.0;   // ReLU(conv + bias)
      }
      hs[ci][pp] = v;
    }
    for (int s = tid; s < 64 * 80; s += 256) {
      int ci = s / 80, c = s % 80;
      double v = 0.0;
      if (c < 15) v = (double)clsw[c * C_ + ci0 + ci];
      else if (c < 75) v = (double)bbw[(c - 15) * C_ + ci0 + ci];
      wl[ci][c] = v;
    }
    __syncthreads();
    for (int ci = 0; ci < 64; ++ci) {
      double xv = hs[ci][px];
#pragma unroll
      for (int k = 0; k < 10; ++k)
        acc[k] = fma(wl[ci][cg * 10 + k], xv, acc[k]);
    }
    __syncthreads();
  }
  int p = p0 + px;
  if (p < HW_) {
#pragma unroll
    for (int k = 0; k < 10; ++k) {
      int c = cg * 10 + k;
      if (c < 15) {
        double z = acc[k] + (double)clsb[c];
        out[(size_t)b * NS_ + c * HW_ + p] = (float)z;
        double s = 1.0 / (1.0 + exp(-z));
        scores[(size_t)b * NS_ + (size_t)p * A_ + c] = s;
      } else if (c < 75) {
        int cbx = c - 15;
        double z = acc[k] + (double)bbb[cbx];
        out[(size_t)B_ * NS_ + (size_t)b * (4 * A_ * HW_) + cbx * HW_ + p] = (float)z;
        deltas[(size_t)b * (4 * NS_) + (size_t)p * (4 * A_) + cbx] = z;
      }
    }
  }
}

// ---------------- select: prefix recomputation (deterministic integer scan) ----------------
__device__ inline u64 compute_prefix(const u32* __restrict__ selhist, int b, int rounds) {
  u64 prefix = 0;
  u32 above = 0;
  for (int rr = 0; rr < rounds; ++rr) {
    const u32* h = selhist + (rr * 2 + b) * 256;
    int shift = 56 - 8 * rr;
    u32 c = above;
    int dsel = 0;
    for (int dd = 255; dd >= 0; --dd) {
      u32 nc = c + h[dd];
      if (nc >= (u32)PRE_) { dsel = dd; break; }
      c = nc;
    }
    prefix |= ((u64)dsel << shift);
    above = c;
  }
  return prefix;
}

__global__ __launch_bounds__(256) void k_hist(const double* __restrict__ scores,
                                              u32* __restrict__ selhist, int r) {
  const int b = blockIdx.y;
  const double* sc = scores + (size_t)b * NS_;
  const int lane = (int)(threadIdx.x & 63);
  const int shift = 56 - 8 * r;
  __shared__ u64 sh_prefix;
  if (threadIdx.x == 0) sh_prefix = (r == 0) ? 0ull : compute_prefix(selhist, b, r);
  __syncthreads();
  const u64 prefix = sh_prefix;
  const u64 himask = (r == 0) ? 0ull : (~0ull << (shift + 8));
  u32* hist = selhist + (r * 2 + b) * 256;
  for (int i = blockIdx.x * 256 + (int)threadIdx.x; i < NS_; i += 64 * 256) {
    u64 k = (u64)__double_as_longlong(sc[i]);
    bool valid = ((k & himask) == (prefix & himask));
    u32 d = (u32)((k >> shift) & 255);
    u64 m = __ballot(valid);
#pragma unroll
    for (int bit = 0; bit < 8; ++bit) {
      u64 bb = __ballot((d >> bit) & 1);
      m &= ((d >> bit) & 1) ? bb : ~bb;
    }
    if (valid && lane == (__ffsll((unsigned long long)m) - 1))
      atomicAdd(&hist[d], (u32)__popcll(m));
  }
}

__global__ __launch_bounds__(256) void k_compact(const double* __restrict__ scores,
                                                 const u32* __restrict__ selhist,
                                                 u32* __restrict__ selcnt,
                                                 u64* __restrict__ selk,
                                                 u32* __restrict__ seli) {
  const int b = blockIdx.y;
  const double* sc = scores + (size_t)b * NS_;
  const int lane = (int)(threadIdx.x & 63);
  __shared__ u64 sh_T;
  if (threadIdx.x == 0) sh_T = compute_prefix(selhist, b, NROUNDS_);
  __syncthreads();
  const u64 T = sh_T;
  for (int i = blockIdx.x * 256 + (int)threadIdx.x; i < NS_; i += 64 * 256) {
    u64 k = (u64)__double_as_longlong(sc[i]);
    bool q = (k >= T);
    u64 bal = __ballot(q);
    if (bal) {
      int leader = __ffsll((unsigned long long)bal) - 1;
      u32 wbase = 0;
      if (lane == leader) wbase = atomicAdd(&selcnt[b], (u32)__popcll(bal));
      wbase = (u32)__shfl((int)wbase, leader);
      if (q) {
        u64 below = (lane == 0) ? 0ull : (~0ull >> (64 - lane));
        u32 pos = wbase + (u32)__popcll(bal & below);
        if (pos < (u32)SORTN_) {
          selk[(size_t)b * SORTN_ + pos] = k;
          seli[(size_t)b * SORTN_ + pos] = (u32)i;
        }
      }
    }
  }
}

// ---------------- K4a: distributed rank count (desc by key, asc idx) ----------------
// grid (8 e-blocks, JCH_ j-chunks, B). Each block counts, for its 1024 owners e,
// how many candidates in its j-chunk outrank e; integer atomicAdd accumulation is
// order-independent -> deterministic. 256 blocks spread the comparisons chip-wide.
__global__ __launch_bounds__(1024) void k_rankcnt(const u64* __restrict__ selk,
                                                  const u32* __restrict__ seli,
                                                  const u32* __restrict__ selcnt,
                                                  u32* __restrict__ rankb) {
  const int b = blockIdx.z;
  int mn = (int)selcnt[b];
  if (mn > SORTN_) mn = SORTN_;
  const int e = blockIdx.x * 1024 + (int)threadIdx.x;
  const bool active = (e < mn);
  u64 ke = 0; u32 ie = 0;
  if (active) {
    ke = selk[(size_t)b * SORTN_ + e];
    ie = seli[(size_t)b * SORTN_ + e];
  }
  const int jlen = (mn + JCH_ - 1) / JCH_;
  const int j0 = blockIdx.y * jlen;
  int j1 = j0 + jlen;
  if (j1 > mn) j1 = mn;
  __shared__ u64 ks[1024];
  __shared__ u32 isx[1024];
  u32 cnt = 0;
  for (int t0 = j0; t0 < j1; t0 += 1024) {
    int j = t0 + (int)threadIdx.x;
    if (j < j1) {
      ks[threadIdx.x] = selk[(size_t)b * SORTN_ + j];
      isx[threadIdx.x] = seli[(size_t)b * SORTN_ + j];
    }
    __syncthreads();
    int lim = j1 - t0;
    if (lim > 1024) lim = 1024;
    if (active) {
      for (int jj = 0; jj < lim; ++jj) {
        u64 kj = ks[jj];
        bool better = (kj > ke) || (kj == ke && isx[jj] < ie);
        cnt += better ? 1u : 0u;
      }
    }
    __syncthreads();
  }
  if (active && cnt) atomicAdd(&rankb[b * SORTN_ + e], cnt);
}

// ---------------- K4b: scatter by rank (ranks are a permutation of [0,mn)) ----------------
__global__ __launch_bounds__(256) void k_scatter(const u64* __restrict__ selk,
                                                 const u32* __restrict__ seli,
                                                 const u32* __restrict__ selcnt,
                                                 const u32* __restrict__ rankb,
                                                 double* __restrict__ ssc,
                                                 u32* __restrict__ sidx) {
  const int b = blockIdx.y;
  int mn = (int)selcnt[b];
  if (mn > SORTN_) mn = SORTN_;
  int e = blockIdx.x * 256 + (int)threadIdx.x;
  if (e < mn) {
    u32 r = rankb[b * SORTN_ + e];
    if (r < (u32)PRE_) {
      ssc[(size_t)b * PRE_ + r] = __longlong_as_double((long long)selk[(size_t)b * SORTN_ + e]);
      sidx[(size_t)b * PRE_ + r] = seli[(size_t)b * SORTN_ + e];
    }
  }
}

// ---------------- K5: box decode + clip + valid (f64, contract off) ----------------
__global__ __launch_bounds__(256) void k_decode(const u32* __restrict__ sidx,
                                                const double* __restrict__ deltas,
                                                const float* __restrict__ anchors,
                                                const float* __restrict__ iminfo,
                                                double* __restrict__ boxes,
                                                double* __restrict__ areas,
                                                u64* __restrict__ vmask) {
#pragma clang fp contract(off)
  const int b = blockIdx.y;
  const int i = blockIdx.x * 256 + (int)threadIdx.x;
  bool valid = false;
  if (i < NPAD_) {
    double x1 = 0, y1 = 0, x2 = 0, y2 = 0, ar = 0;
    if (i < PRE_) {
      u32 idx = sidx[(size_t)b * PRE_ + i];
      int p = (int)idx / A_, a = (int)idx % A_;
      int yy = p / W_, xx = p % W_;
      double sx = xx * 16.0, sy = yy * 16.0;
      double b0 = sx + (double)anchors[a * 4 + 0];
      double b1 = sy + (double)anchors[a * 4 + 1];
      double b2 = sx + (double)anchors[a * 4 + 2];
      double b3 = sy + (double)anchors[a * 4 + 3];
      double wdt = b2 - b0 + 1.0, hgt = b3 - b1 + 1.0;
      double cx = b0 + 0.5 * wdt, cy = b1 + 0.5 * hgt;
      const double* d = deltas + (size_t)b * (4 * NS_) + (size_t)idx * 4;
      double dx = d[0], dy = d[1];
      double dw = d[2] < CLIP_ ? d[2] : CLIP_;
      double dh = d[3] < CLIP_ ? d[3] : CLIP_;
      double pcx = dx * wdt + cx, pcy = dy * hgt + cy;
      double pw = exp(dw) * wdt, ph = exp(dh) * hgt;
      x1 = pcx - 0.5 * pw;
      y1 = pcy - 0.5 * ph;
      x2 = pcx + 0.5 * pw - 1.0;
      y2 = pcy + 0.5 * ph - 1.0;
      double imh = (double)iminfo[b * 3 + 0];
      double imw = (double)iminfo[b * 3 + 1];
      x1 = x1 < 0.0 ? 0.0 : (x1 > imw - 1.0 ? imw - 1.0 : x1);
      y1 = y1 < 0.0 ? 0.0 : (y1 > imh - 1.0 ? imh - 1.0 : y1);
      x2 = x2 < 0.0 ? 0.0 : (x2 > imw - 1.0 ? imw - 1.0 : x2);
      y2 = y2 < 0.0 ? 0.0 : (y2 > imh - 1.0 ? imh - 1.0 : y2);
      double wss = x2 - x1 + 1.0, hss = y2 - y1 + 1.0;
      double xc = x1 + wss / 2.0, yc = y1 + hss / 2.0;
      valid = (wss >= 0.0) && (hss >= 0.0) && (xc < imw) && (yc < imh);
      ar = wss * hss;
    }
    double* bx = boxes + ((size_t)b * NPAD_ + i) * 4;
    bx[0] = x1; bx[1] = y1; bx[2] = x2; bx[3] = y2;
    areas[(size_t)b * NPAD_ + i] = ar;
  }
  u64 bal = __ballot(valid);
  if ((threadIdx.x & 63) == 0) {
    int w = i >> 6;
    if (w < WORDS_) vmask[b * WORDS_ + w] = bal;
  }
}

// ---------------- K6: suppression bitmask v2 (4 row-blocks/block, sparse stores) ----------------
__global__ __launch_bounds__(256) void k_mask(const double* __restrict__ boxes,
                                              const double* __restrict__ areas,
                                              u64* __restrict__ mask) {
#pragma clang fp contract(off)
  const int b = blockIdx.z;
  const int wc = blockIdx.x;        // column word [0,94)
  const int rq = blockIdx.y;        // row quad: rows [rq*256, rq*256+256)
  if (wc * 64 + 63 <= rq * 256) return;  // no j > i anywhere in block (uniform)
  const int i = rq * 256 + (int)threadIdx.x;
  __shared__ double cbx[64][4];
  __shared__ double car[64];
  if (threadIdx.x < 64) {
    int sj = wc * 64 + (int)threadIdx.x;  // <= 6015 < NPAD_
    const double* pj = boxes + ((size_t)b * NPAD_ + sj) * 4;
    cbx[threadIdx.x][0] = pj[0];
    cbx[threadIdx.x][1] = pj[1];
    cbx[threadIdx.x][2] = pj[2];
    cbx[threadIdx.x][3] = pj[3];
    car[threadIdx.x] = areas[(size_t)b * NPAD_ + sj];
  }
  __syncthreads();
  if (i >= PRE_) return;
  int jmax = PRE_ - wc * 64;
  if (jmax > 64) jmax = 64;
  if (wc * 64 + jmax - 1 <= i) return;  // this row has no j > i in the word
  const double* bi = boxes + ((size_t)b * NPAD_ + i) * 4;
  double x1 = bi[0], y1 = bi[1], x2 = bi[2], y2 = bi[3];
  double ai = areas[(size_t)b * NPAD_ + i];
  u64 m = 0;
  for (int j2 = 0; j2 < jmax; ++j2) {
    int j = wc * 64 + j2;
    if (j > i) {
      double ix1 = x1 > cbx[j2][0] ? x1 : cbx[j2][0];
      double iy1 = y1 > cbx[j2][1] ? y1 : cbx[j2][1];
      double ix2 = x2 < cbx[j2][2] ? x2 : cbx[j2][2];
      double iy2 = y2 < cbx[j2][3] ? y2 : cbx[j2][3];
      double iw = ix2 - ix1 + 1.0;
      if (iw < 0.0) iw = 0.0;
      double ih = iy2 - iy1 + 1.0;
      if (ih < 0.0) ih = 0.0;
      double inter = iw * ih;
      double iou = inter / (ai + car[j2] - inter);
      if (iou > NMS_T) m |= (1ull << j2);
    }
  }
  if (m) mask[((size_t)b * NPAD_ + i) * WORDS_ + wc] = m;
}

// ---------------- K7: greedy NMS closure scan (survivor chain, dg prefetch, 8-wide ORs) ----------------
__global__ __launch_bounds__(64) void k_scan(const u64* __restrict__ mask,
                                             const u64* __restrict__ vmask,
                                             u64* __restrict__ keepm) {
  const int b = blockIdx.x;
  const int lane = (int)threadIdx.x;
  u64 rem0 = ~vmask[b * WORDS_ + lane];  // lane holds word `lane` (dead-bits)
  u64 rem1 = (lane < WORDS_ - 64) ? ~vmask[b * WORDS_ + 64 + lane] : ~0ull;
  const u64* mb = mask + (size_t)b * NPAD_ * WORDS_;
  int kept = 0;
  int Bb = 0;
  // prefetch diagonal block 0
  u64 dgnext = (lane < 64) ? mb[(size_t)lane * WORDS_ + 0] : 0ull;
  for (; Bb < WORDS_ && kept < POST_; ++Bb) {
    const int base = Bb * 64;
    int lim = PRE_ - base;
    if (lim > 64) lim = 64;
    u64 dg = (lane < lim) ? dgnext : 0ull;
    // prefetch next diagonal block (latency hides under the serial chain)
    if (Bb + 1 < WORDS_) {
      int nbase = (Bb + 1) * 64;
      int nlim = PRE_ - nbase;
      if (nlim > 64) nlim = 64;
      dgnext = (lane < nlim) ? mb[(size_t)(nbase + lane) * WORDS_ + (Bb + 1)] : 0ull;
    }
    u64 cur = (Bb < 64) ? __shfl(rem0, Bb) : __shfl(rem1, Bb - 64);
    if (lim < 64) cur |= (~0ull) << lim;
    u64 kb = 0;
    while (cur != ~0ull) {
      int t = __ffsll((unsigned long long)~cur) - 1;
      kb |= 1ull << t;
      cur |= __shfl(dg, t);
      cur |= 1ull << t;
      if (++kept >= POST_) break;
    }
    // deferred row-ORs, 8 rows' loads in flight per step (kb is wave-uniform)
    u64 or0 = 0, or1 = 0;
    u64 k2 = kb;
    while (k2) {
      int tt[8];
      int nt = 0;
#pragma unroll
      for (int u = 0; u < 8; ++u) {
        if (k2) {
          tt[u] = __ffsll((unsigned long long)k2) - 1;
          k2 &= k2 - 1;
          ++nt;
        } else {
          tt[u] = -1;
        }
      }
      u64 lo[8], hi[8];
#pragma unroll
      for (int u = 0; u < 8; ++u) {
        lo[u] = 0; hi[u] = 0;
        if (tt[u] >= 0) {
          const u64* mr = mb + (size_t)(base + tt[u]) * WORDS_;
          lo[u] = mr[lane];
          hi[u] = (lane < WORDS_ - 64) ? mr[64 + lane] : 0ull;
        }
      }
      (void)nt;
      or0 |= ((lo[0] | lo[1]) | (lo[2] | lo[3])) | ((lo[4] | lo[5]) | (lo[6] | lo[7]));
      or1 |= ((hi[0] | hi[1]) | (hi[2] | hi[3])) | ((hi[4] | hi[5]) | (hi[6] | hi[7]));
    }
    rem0 |= or0;
    rem1 |= or1;
    if (lane == 0) keepm[b * WORDS_ + Bb] = kb;
  }
  for (int w = Bb + lane; w < WORDS_; w += 64)
    keepm[b * WORDS_ + w] = 0ull;
}

// ---------------- K8: finalize rois + probs (kept in order, then not-kept with -1) ----------------
__global__ __launch_bounds__(256) void k_final(const u64* __restrict__ keepm,
                                               const double* __restrict__ boxes,
                                               const double* __restrict__ ssc,
                                               float* __restrict__ out) {
  const int b = blockIdx.x;
  __shared__ u32 pk[WORDS_ + 1];
  __shared__ u64 km_s[WORDS_];
  for (int w = threadIdx.x; w < WORDS_; w += 256) km_s[w] = keepm[b * WORDS_ + w];
  __syncthreads();
  if (threadIdx.x == 0) {
    u32 a = 0;
    for (int w = 0; w < WORDS_; ++w) {
      pk[w] = a;
      a += (u32)__popcll(km_s[w]);
    }
    pk[WORDS_] = a;
  }
  __syncthreads();
  const u32 K = pk[WORDS_];
  for (int i = threadIdx.x; i < PRE_; i += 256) {
    int w = i >> 6, t = i & 63;
    u64 km = km_s[w];
    u32 before = pk[w] + (u32)__popcll(km & ((1ull << t) - 1ull));
    bool kp = (km >> t) & 1ull;
    int slot = kp ? (int)before : (int)K + (i - (int)before);
    if (slot < POST_) {
      const double* bx = boxes + ((size_t)b * NPAD_ + i) * 4;
      float* ro = out + OUT_ROIS_ + ((size_t)b * POST_ + slot) * 5;
      ro[0] = (float)b;
      ro[1] = (float)bx[0];
      ro[2] = (float)bx[1];
      ro[3] = (float)bx[2];
      ro[4] = (float)bx[3];
      out[OUT_PROBS_ + b * POST_ + slot] = kp ? (float)ssc[(size_t)b * PRE_ + i] : -1.0f;
    }
  }
}

extern "C" void kernel_launch(void* const* d_in, const int* in_sizes, int n_in,
                              void* d_out, int out_size, void* d_ws, size_t ws_size,
                              hipStream_t stream) {
  (void)in_sizes; (void)n_in; (void)out_size;
  const float* x = (const float*)d_in[0];
  const float* iminfo = (const float*)d_in[1];
  const float* convw = (const float*)d_in[2];
  const float* convb = (const float*)d_in[3];
  const float* clsw = (const float*)d_in[4];
  const float* clsb = (const float*)d_in[5];
  const float* bbw = (const float*)d_in[6];
  const float* bbb = (const float*)d_in[7];
  const float* anchors = (const float*)d_in[8];
  float* out = (float*)d_out;

  char* ws = (char*)d_ws;
  size_t off = 0;
  auto alloc = [&](size_t bytes) -> void* {
    void* p = ws + off;
    off += (bytes + 255) & ~(size_t)255;
    return p;
  };
  const size_t HB = (size_t)B_ * C_ * HW_ * 8;                  // 34.4 MB
  double* wt64 = (double*)alloc((size_t)C_ * 9 * C_ * 8);       // 18.9 MB
  double* h0 = (double*)alloc(HB);
  double* h1 = (double*)alloc(HB);
  double* scores = (double*)alloc((size_t)B_ * NS_ * 8);        // 1 MB
  double* deltas = (double*)alloc((size_t)B_ * NS_ * 4 * 8);    // 4 MB
  u64* selk = (u64*)alloc((size_t)B_ * SORTN_ * 8);
  u32* seli = (u32*)alloc((size_t)B_ * SORTN_ * 4);
  double* ssc = (double*)alloc((size_t)B_ * PRE_ * 8);
  u32* sidx = (u32*)alloc((size_t)B_ * PRE_ * 4);
  double* boxes = (double*)alloc((size_t)B_ * NPAD_ * 4 * 8);
  double* areas = (double*)alloc((size_t)B_ * NPAD_ * 8);
  u64* vmask = (u64*)alloc((size_t)B_ * WORDS_ * 8);
  u64* mask = (u64*)alloc((size_t)B_ * NPAD_ * WORDS_ * 8);     // 9 MB
  u64* keepm = (u64*)alloc((size_t)B_ * WORDS_ * 8);
  u32* selcnt = (u32*)alloc(2 * 4);
  u32* selhist = (u32*)alloc((size_t)NROUNDS_ * 2 * 256 * 4);
  u32* rankb = (u32*)alloc((size_t)B_ * SORTN_ * 4);

  // split-K=8 needs 2 extra partial buffers; fall back to proven split-K=4 if
  // the workspace is too small (decision depends only on ws_size: deterministic).
  const bool k8 = (ws_size >= off + 2 * (HB + 256) + 256);
  double* h2 = h0;
  double* h3 = h1;
  int nbuf = 2;
  if (k8) {
    h2 = (double*)alloc(HB);
    h3 = (double*)alloc(HB);
    nbuf = 4;
  }

  k_init<<<(B_ * C_ * HW_ + 255) / 256, 256, 0, stream>>>(
      convw, wt64, h0, h1, h2, h3, nbuf, mask, selcnt, selhist, rankb);
  if (k8)
    k_conv3<3><<<dim3(7, 5, 256), 256, 0, stream>>>(x, wt64, h0, h1, h2, h3);
  else
    k_conv3<2><<<dim3(7, 5, 128), 256, 0, stream>>>(x, wt64, h0, h1, h2, h3);
  k_conv1<<<dim3(132, 2), 256, 0, stream>>>(h0, h1, h2, h3, nbuf, convb, clsw, clsb,
                                            bbw, bbb, out, scores, deltas);
  for (int r = 0; r < NROUNDS_; ++r)
    k_hist<<<dim3(64, 2), 256, 0, stream>>>(scores, selhist, r);
  k_compact<<<dim3(64, 2), 256, 0, stream>>>(scores, selhist, selcnt, selk, seli);
  k_rankcnt<<<dim3(8, JCH_, 2), 1024, 0, stream>>>(selk, seli, selcnt, rankb);
  k_scatter<<<dim3(32, 2), 256, 0, stream>>>(selk, seli, selcnt, rankb, ssc, sidx);
  k_decode<<<dim3(24, 2), 256, 0, stream>>>(sidx, deltas, anchors, iminfo, boxes, areas, vmask);
  k_mask<<<dim3(94, 24, 2), 256, 0, stream>>>(boxes, areas, mask);
  k_scan<<<2, 64, 0, stream>>>(mask, vmask, keepm);
  k_final<<<2, 256, 0, stream>>>(keepm, boxes, ssc, out);
}